// Round 10
// baseline (325.167 us; speedup 1.0000x reference)
//
#include <hip/hip_runtime.h>
#include <math.h>

// Problem constants
#define NPOS 65536   // B*H*W = 8*1*8192
#define NCH  128
#define DELTA 0.008f // argmax top-2 gap below which we recompute in exact fp32

// ws layout (float element offsets)
#define OFF_XR   0u                       // XRB bf16 [n][128] lives here (16 MB of 32 MB region)
#define OFF_W1T  8388608u                 // fixup fp32 [cin][cout]
#define OFF_W2T  (OFF_W1T + 16384u)
#define OFF_W3T  (OFF_W2T + 16384u)
#define OFF_B1F  (OFF_W3T + 16384u)
#define OFF_BRF  (OFF_B1F + 128u)
#define OFF_B2F  (OFF_BRF + 128u)
#define OFF_B3F  (OFF_B2F + 128u)         // 132 (129 used)
#define OFF_BF16 (OFF_B3F + 132u)         // ushort region
#define OFF_INT  (OFF_BF16 + 329728u)     // int region (bf16 region = 659456 ushorts)

// ushort offsets inside bf16 region
#define UW1H 0u
#define UW1L 16384u
#define UWRH 32768u
#define UWRL 49152u
#define UW2H 65536u
#define UW2L 81920u
#define UW3H 98304u      // [144][128]; row128=mask, rows129..143=0
#define UW3L 116736u
#define UW2K 135168u     // cm2w bf16 transposed [k][out][ci] : 524288 -> end 659456

// frag-major LDS: [mg][kt][lane][8 ushorts], +32-ushort pad per mg
#define NST 2080         // 4*512 + 32

typedef short bf16x8 __attribute__((ext_vector_type(8)));
typedef float f32x4 __attribute__((ext_vector_type(4)));
#define MFMA16 __builtin_amdgcn_mfma_f32_16x16x32_bf16

__device__ __forceinline__ float lrelu(float v) { return v >= 0.0f ? v : 0.01f * v; }
__device__ __forceinline__ unsigned short f2bf(float f) {
    unsigned u = __float_as_uint(f);
    return (unsigned short)((u + 0x7fffu + ((u >> 16) & 1u)) >> 16);
}
__device__ __forceinline__ float bf2f(unsigned short h) {
    return __uint_as_float(((unsigned)h) << 16);
}
__device__ __forceinline__ unsigned long long pack4(unsigned short a, unsigned short b,
                                                    unsigned short c, unsigned short d) {
    return (unsigned long long)a | ((unsigned long long)b << 16)
         | ((unsigned long long)c << 32) | ((unsigned long long)d << 48);
}

// ---------------------------------------------------------------------------
// prep: blocks 0..127: fold BN, fp32 fixup tables, bf16 hi/lo planes, biases.
//       blocks 128..255: cm2w -> bf16 transposed [k][out][ci] via LDS tile.
// ---------------------------------------------------------------------------
__global__ void k_prep(const float* __restrict__ cl1_w, const float* __restrict__ cl1_b,
                       const float* __restrict__ g1, const float* __restrict__ be1,
                       const float* __restrict__ mu1, const float* __restrict__ va1,
                       const float* __restrict__ cl2_w, const float* __restrict__ cl2_b,
                       const float* __restrict__ cl3_w, const float* __restrict__ cl3_b,
                       const float* __restrict__ reg1_w, const float* __restrict__ reg1_b,
                       const float* __restrict__ gr, const float* __restrict__ ber,
                       const float* __restrict__ mur, const float* __restrict__ var_,
                       const float* __restrict__ cm2w,
                       float* __restrict__ ws_f, unsigned short* __restrict__ wbf,
                       int* __restrict__ hist, int* __restrict__ fixcnt)
{
    const int bid = blockIdx.x;
    const int t = threadIdx.x;
    if (bid >= 128) {                       // cm2w transpose, one k per block
        __shared__ float tl[32 * 132];      // [o][ci]
        int k = bid - 128;
        #pragma unroll
        for (int i = 0; i < 32; ++i) {
            float v = cm2w[(unsigned)k * 4096u + i * 128 + t];  // coalesced
            int ci = i * 4 + (t >> 5), o = t & 31;
            tl[o * 132 + ci] = v;
        }
        __syncthreads();
        #pragma unroll
        for (int i = 0; i < 32; ++i)
            wbf[UW2K + (unsigned)k * 4096u + i * 128 + t] = f2bf(tl[i * 132 + t]);
        return;
    }
    int tid = bid * 128 + t;                // 16384 threads
    int cin = tid >> 7, cout = tid & 127;
    float s1 = g1[cout] / sqrtf(va1[cout] + 1e-5f);
    float sr = gr[cout] / sqrtf(var_[cout] + 1e-5f);
    float w1 = cl1_w[cout * 128 + cin] * s1;
    float wr = reg1_w[cout * 128 + cin] * sr;
    float w2 = cl2_w[cout * 128 + cin];
    float w3 = cl3_w[cout * 128 + cin];
    ws_f[OFF_W1T + tid] = w1;
    ws_f[OFF_W2T + tid] = w2;
    ws_f[OFF_W3T + tid] = w3;
    int j = cout * 128 + cin;
    unsigned short h;
    h = f2bf(w1); wbf[UW1H + j] = h; wbf[UW1L + j] = f2bf(w1 - bf2f(h));
    h = f2bf(wr); wbf[UWRH + j] = h; wbf[UWRL + j] = f2bf(wr - bf2f(h));
    h = f2bf(w2); wbf[UW2H + j] = h; wbf[UW2L + j] = f2bf(w2 - bf2f(h));
    h = f2bf(w3); wbf[UW3H + j] = h; wbf[UW3L + j] = f2bf(w3 - bf2f(h));
    if (tid < 2048) {               // W3 rows 128..143: mask row then zeros
        int r = tid >> 7, ci = tid & 127;
        float v = (r == 0) ? cl3_w[128 * 128 + ci] : 0.0f;
        int jj = (128 + r) * 128 + ci;
        h = f2bf(v); wbf[UW3H + jj] = h; wbf[UW3L + jj] = f2bf(v - bf2f(h));
    }
    if (tid < 128) {
        float s1b = g1[tid] / sqrtf(va1[tid] + 1e-5f);
        float srb = gr[tid] / sqrtf(var_[tid] + 1e-5f);
        ws_f[OFF_B1F + tid] = cl1_b[tid] * s1b + be1[tid] - mu1[tid] * s1b;
        ws_f[OFF_BRF + tid] = reg1_b[tid] * srb + ber[tid] - mur[tid] * srb;
        ws_f[OFF_B2F + tid] = cl2_b[tid];
        hist[tid] = 0;
    }
    if (tid < 129) ws_f[OFF_B3F + tid] = cl3_b[tid];
    if (tid == 0) fixcnt[0] = 0;
}

// ---------------------------------------------------------------------------
// FUSED pipeline on MFMA — R5/R9 measured structure. ONE change: xr stored
// bf16 (ushort4, 16 rows x 32B contiguous per instr) instead of fp32 scalars.
// hist atomics restored to epilogue (drops the separate k_hist pass).
// ---------------------------------------------------------------------------
__global__ __launch_bounds__(256, 2)
void k_fused(const float* __restrict__ X, const float* __restrict__ wsf,
             const unsigned short* __restrict__ wbf,
             unsigned short* __restrict__ XRB, float* __restrict__ out_mask,
             int* __restrict__ inds, int* __restrict__ hist,
             int* __restrict__ fixcnt, int* __restrict__ fixlist)
{
    __shared__ __align__(16) unsigned short XBh[64 * 136];
    __shared__ __align__(16) unsigned short XBl[64 * 136];
    __shared__ float sm1[4 * 64];
    __shared__ float sm2[4 * 64];
    __shared__ int   si1[4 * 64];

    const int t = threadIdx.x;
    const int lane = t & 63;
    const int cl16 = lane & 15;           // col / n within fragment
    const int q8 = (lane >> 4) * 8;       // k-offset within fragment
    const int q4 = (lane >> 4) * 4;       // row-offset within D fragment
    const int wv = __builtin_amdgcn_readfirstlane(t >> 6);
    const unsigned nt64 = blockIdx.x * 64u;
    const unsigned base = nt64 + (nt64 >> 13) * 1040384u;   // b*1048576 + w0

    const unsigned short* W1H = wbf + UW1H; const unsigned short* W1L = wbf + UW1L;
    const unsigned short* WRH = wbf + UWRH; const unsigned short* WRL = wbf + UWRL;
    const unsigned short* W2H = wbf + UW2H; const unsigned short* W2L = wbf + UW2L;
    const unsigned short* W3H = wbf + UW3H; const unsigned short* W3L = wbf + UW3L;
    const float* b1f = wsf + OFF_B1F;
    const float* brf = wsf + OFF_BRF;
    const float* b2f = wsf + OFF_B2F;
    const float* b3f = wsf + OFF_B3F;

    const f32x4 vzero = {0.f, 0.f, 0.f, 0.f};

    // ---- stage x tile -> bf16 hi/lo planes [pos][cin] ----
    {
        const int pos = t & 63, cig = t >> 6;      // cig: 0..3
        #pragma unroll
        for (int l = 0; l < 8; ++l) {
            int ci0 = cig * 32 + l * 4;
            float v0 = X[base + (unsigned)(ci0 + 0) * 8192u + pos];
            float v1 = X[base + (unsigned)(ci0 + 1) * 8192u + pos];
            float v2 = X[base + (unsigned)(ci0 + 2) * 8192u + pos];
            float v3 = X[base + (unsigned)(ci0 + 3) * 8192u + pos];
            unsigned short h0 = f2bf(v0), h1 = f2bf(v1), h2 = f2bf(v2), h3 = f2bf(v3);
            unsigned long long ph = pack4(h0, h1, h2, h3);
            unsigned long long pl = pack4(f2bf(v0 - bf2f(h0)), f2bf(v1 - bf2f(h1)),
                                          f2bf(v2 - bf2f(h2)), f2bf(v3 - bf2f(h3)));
            *(unsigned long long*)&XBh[pos * 136 + ci0] = ph;
            *(unsigned long long*)&XBl[pos * 136 + ci0] = pl;
        }
    }
    __syncthreads();

    // ---- P1: y1 (W1) and xr (WR) in one pass over B frags ----
    f32x4 aY[2][4], aR[2][4];
    #pragma unroll
    for (int m = 0; m < 2; ++m)
        #pragma unroll
        for (int n = 0; n < 4; ++n) { aY[m][n] = vzero; aR[m][n] = vzero; }
    #pragma unroll
    for (int kt = 0; kt < 4; ++kt) {
        bf16x8 Bh[4], Bl[4];
        #pragma unroll
        for (int n = 0; n < 4; ++n) {
            int bo = (n * 16 + cl16) * 136 + kt * 32 + q8;
            Bh[n] = *(const bf16x8*)&XBh[bo];
            Bl[n] = *(const bf16x8*)&XBl[bo];
        }
        #pragma unroll
        for (int m = 0; m < 2; ++m) {
            int ao = (wv * 32 + m * 16 + cl16) * 128 + kt * 32 + q8;
            bf16x8 a1h = *(const bf16x8*)&W1H[ao], a1l = *(const bf16x8*)&W1L[ao];
            bf16x8 arh = *(const bf16x8*)&WRH[ao], arl = *(const bf16x8*)&WRL[ao];
            #pragma unroll
            for (int n = 0; n < 4; ++n) {
                aY[m][n] = MFMA16(a1h, Bl[n], aY[m][n], 0, 0, 0);
                aY[m][n] = MFMA16(a1l, Bh[n], aY[m][n], 0, 0, 0);
                aY[m][n] = MFMA16(a1h, Bh[n], aY[m][n], 0, 0, 0);
                aR[m][n] = MFMA16(arh, Bl[n], aR[m][n], 0, 0, 0);
                aR[m][n] = MFMA16(arl, Bh[n], aR[m][n], 0, 0, 0);
                aR[m][n] = MFMA16(arh, Bh[n], aR[m][n], 0, 0, 0);
            }
        }
    }
    __syncthreads();                       // all P1 reads of XB done

    // xr epilogue -> global XRB[n][c] bf16 (ushort4; 16 rows x 32B contiguous)
    {
        #pragma unroll
        for (int m = 0; m < 2; ++m) {
            int cb = wv * 32 + m * 16 + q4;
            float br0 = brf[cb], br1 = brf[cb + 1], br2 = brf[cb + 2], br3 = brf[cb + 3];
            #pragma unroll
            for (int n = 0; n < 4; ++n) {
                unsigned pb = (nt64 + n * 16 + cl16) * 128u + cb;
                ushort4 xo;
                xo.x = f2bf(lrelu(aR[m][n][0] + br0));
                xo.y = f2bf(lrelu(aR[m][n][1] + br1));
                xo.z = f2bf(lrelu(aR[m][n][2] + br2));
                xo.w = f2bf(lrelu(aR[m][n][3] + br3));
                *(ushort4*)&XRB[pb] = xo;
            }
        }
    }
    // y1 epilogue -> XB planes
    {
        #pragma unroll
        for (int m = 0; m < 2; ++m) {
            int cb = wv * 32 + m * 16 + q4;
            float b0 = b1f[cb], b1 = b1f[cb + 1], b2 = b1f[cb + 2], b3 = b1f[cb + 3];
            #pragma unroll
            for (int n = 0; n < 4; ++n) {
                float v0 = lrelu(aY[m][n][0] + b0), v1 = lrelu(aY[m][n][1] + b1);
                float v2 = lrelu(aY[m][n][2] + b2), v3 = lrelu(aY[m][n][3] + b3);
                unsigned short h0 = f2bf(v0), h1 = f2bf(v1), h2 = f2bf(v2), h3 = f2bf(v3);
                unsigned long long ph = pack4(h0, h1, h2, h3);
                unsigned long long pl = pack4(f2bf(v0 - bf2f(h0)), f2bf(v1 - bf2f(h1)),
                                              f2bf(v2 - bf2f(h2)), f2bf(v3 - bf2f(h3)));
                int idx = (n * 16 + cl16) * 136 + cb;
                *(unsigned long long*)&XBh[idx] = ph;
                *(unsigned long long*)&XBl[idx] = pl;
            }
        }
    }
    __syncthreads();

    // ---- P2: y2 = lrelu(W2 y1 + b2) ----
    f32x4 aZ[2][4];
    #pragma unroll
    for (int m = 0; m < 2; ++m)
        #pragma unroll
        for (int n = 0; n < 4; ++n) aZ[m][n] = vzero;
    #pragma unroll
    for (int kt = 0; kt < 4; ++kt) {
        bf16x8 Bh[4], Bl[4];
        #pragma unroll
        for (int n = 0; n < 4; ++n) {
            int bo = (n * 16 + cl16) * 136 + kt * 32 + q8;
            Bh[n] = *(const bf16x8*)&XBh[bo];
            Bl[n] = *(const bf16x8*)&XBl[bo];
        }
        #pragma unroll
        for (int m = 0; m < 2; ++m) {
            int ao = (wv * 32 + m * 16 + cl16) * 128 + kt * 32 + q8;
            bf16x8 ah = *(const bf16x8*)&W2H[ao], al = *(const bf16x8*)&W2L[ao];
            #pragma unroll
            for (int n = 0; n < 4; ++n) {
                aZ[m][n] = MFMA16(ah, Bl[n], aZ[m][n], 0, 0, 0);
                aZ[m][n] = MFMA16(al, Bh[n], aZ[m][n], 0, 0, 0);
                aZ[m][n] = MFMA16(ah, Bh[n], aZ[m][n], 0, 0, 0);
            }
        }
    }
    __syncthreads();
    {
        #pragma unroll
        for (int m = 0; m < 2; ++m) {
            int cb = wv * 32 + m * 16 + q4;
            float b0 = b2f[cb], b1 = b2f[cb + 1], b2 = b2f[cb + 2], b3 = b2f[cb + 3];
            #pragma unroll
            for (int n = 0; n < 4; ++n) {
                float v0 = lrelu(aZ[m][n][0] + b0), v1 = lrelu(aZ[m][n][1] + b1);
                float v2 = lrelu(aZ[m][n][2] + b2), v3 = lrelu(aZ[m][n][3] + b3);
                unsigned short h0 = f2bf(v0), h1 = f2bf(v1), h2 = f2bf(v2), h3 = f2bf(v3);
                unsigned long long ph = pack4(h0, h1, h2, h3);
                unsigned long long pl = pack4(f2bf(v0 - bf2f(h0)), f2bf(v1 - bf2f(h1)),
                                              f2bf(v2 - bf2f(h2)), f2bf(v3 - bf2f(h3)));
                int idx = (n * 16 + cl16) * 136 + cb;
                *(unsigned long long*)&XBh[idx] = ph;
                *(unsigned long long*)&XBl[idx] = pl;
            }
        }
    }
    __syncthreads();

    // ---- P3: logits (+ mask row on wave 3) ----
    f32x4 aL[2][4], aM[4];
    #pragma unroll
    for (int m = 0; m < 2; ++m)
        #pragma unroll
        for (int n = 0; n < 4; ++n) aL[m][n] = vzero;
    #pragma unroll
    for (int n = 0; n < 4; ++n) aM[n] = vzero;
    #pragma unroll
    for (int kt = 0; kt < 4; ++kt) {
        bf16x8 Bh[4], Bl[4];
        #pragma unroll
        for (int n = 0; n < 4; ++n) {
            int bo = (n * 16 + cl16) * 136 + kt * 32 + q8;
            Bh[n] = *(const bf16x8*)&XBh[bo];
            Bl[n] = *(const bf16x8*)&XBl[bo];
        }
        #pragma unroll
        for (int m = 0; m < 2; ++m) {
            int ao = (wv * 32 + m * 16 + cl16) * 128 + kt * 32 + q8;
            bf16x8 ah = *(const bf16x8*)&W3H[ao], al = *(const bf16x8*)&W3L[ao];
            #pragma unroll
            for (int n = 0; n < 4; ++n) {
                aL[m][n] = MFMA16(ah, Bl[n], aL[m][n], 0, 0, 0);
                aL[m][n] = MFMA16(al, Bh[n], aL[m][n], 0, 0, 0);
                aL[m][n] = MFMA16(ah, Bh[n], aL[m][n], 0, 0, 0);
            }
        }
        if (wv == 3) {   // mask row block (rows 128..143, only row 128 used)
            int ao = (128 + cl16) * 128 + kt * 32 + q8;
            bf16x8 ah = *(const bf16x8*)&W3H[ao], al = *(const bf16x8*)&W3L[ao];
            #pragma unroll
            for (int n = 0; n < 4; ++n) {
                aM[n] = MFMA16(ah, Bl[n], aM[n], 0, 0, 0);
                aM[n] = MFMA16(al, Bh[n], aM[n], 0, 0, 0);
                aM[n] = MFMA16(ah, Bh[n], aM[n], 0, 0, 0);
            }
        }
    }

    // per-lane top-2 over its 8 couts (ascending cout = numpy first-tie rule)
    {
        float bb[2][4];
        #pragma unroll
        for (int m = 0; m < 2; ++m) {
            int cb = wv * 32 + m * 16 + q4;
            bb[m][0] = b3f[cb]; bb[m][1] = b3f[cb + 1];
            bb[m][2] = b3f[cb + 2]; bb[m][3] = b3f[cb + 3];
        }
        float m1[4], m2[4]; int i1[4];
        #pragma unroll
        for (int n = 0; n < 4; ++n) {
            m1[n] = -1e30f; m2[n] = -1e30f; i1[n] = 0;
            #pragma unroll
            for (int m = 0; m < 2; ++m) {
                int cb = wv * 32 + m * 16 + q4;
                #pragma unroll
                for (int r = 0; r < 4; ++r) {
                    float v = aL[m][n][r] + bb[m][r];
                    if (v > m1[n]) { m2[n] = m1[n]; m1[n] = v; i1[n] = cb + r; }
                    else if (v > m2[n]) m2[n] = v;
                }
            }
        }
        #pragma unroll
        for (int off = 16; off <= 32; off <<= 1) {
            #pragma unroll
            for (int n = 0; n < 4; ++n) {
                float om1 = __shfl_xor(m1[n], off);
                float om2 = __shfl_xor(m2[n], off);
                int   oi1 = __shfl_xor(i1[n], off);
                if (om1 > m1[n] || (om1 == m1[n] && oi1 < i1[n])) {
                    m2[n] = fmaxf(m1[n], om2); m1[n] = om1; i1[n] = oi1;
                } else {
                    m2[n] = fmaxf(m2[n], om1);
                }
            }
        }
        if ((lane >> 4) == 0) {
            #pragma unroll
            for (int n = 0; n < 4; ++n) {
                sm1[wv * 64 + n * 16 + cl16] = m1[n];
                sm2[wv * 64 + n * 16 + cl16] = m2[n];
                si1[wv * 64 + n * 16 + cl16] = i1[n];
            }
        }
    }
    if (wv == 3 && (lane >> 4) == 0) {
        float mb = b3f[128];
        #pragma unroll
        for (int n = 0; n < 4; ++n)
            out_mask[nt64 + n * 16 + cl16] = lrelu(aM[n][0] + mb);
    }
    __syncthreads();
    if (t < 64) {
        float m1 = sm1[t], m2 = sm2[t];
        int i1 = si1[t];
        #pragma unroll
        for (int w = 1; w < 4; ++w) {     // ascending wv = ascending cout
            float v1 = sm1[w * 64 + t];
            float v2 = sm2[w * 64 + t];
            int   vi = si1[w * 64 + t];
            if (v1 > m1) { m2 = fmaxf(m1, v2); m1 = v1; i1 = vi; }
            else         { m2 = fmaxf(m2, v1); }
        }
        int n = nt64 + t;
        inds[n] = i1;
        atomicAdd(&hist[i1], 1);
        if (m1 - m2 < DELTA) {
            int slot = atomicAdd(fixcnt, 1);
            fixlist[slot] = n;
        }
    }
}

// ---------------------------------------------------------------------------
// fixup: ONE WAVE per flagged position, exact fp32, lane-coalesced weights.
// Delta-corrects hist on flip.
// ---------------------------------------------------------------------------
__global__ __launch_bounds__(256, 4)
void k_fix(const float* __restrict__ X, const float* __restrict__ wsf,
           const int* __restrict__ fixcnt, const int* __restrict__ fixlist,
           int* __restrict__ inds, int* __restrict__ hist)
{
    const int cnt = fixcnt[0];
    const int t = threadIdx.x;
    const int lane = t & 63;
    const int wv = t >> 6;
    const float* W1T = wsf + OFF_W1T;
    const float* W2T = wsf + OFF_W2T;
    const float* W3T = wsf + OFF_W3T;
    const float* b1f = wsf + OFF_B1F;
    const float* b2f = wsf + OFF_B2F;
    const float* b3f = wsf + OFF_B3F;

    for (int idx = blockIdx.x * 4 + wv; idx < cnt; idx += 1024) {
        int n = fixlist[idx];
        const float* xb = X + (unsigned)(n >> 13) * 1048576u + (unsigned)(n & 8191);
        float x0 = xb[(unsigned)lane * 8192u];
        float x1 = xb[(unsigned)(64 + lane) * 8192u];
        float a0, a1;
        a0 = 0.f; a1 = 0.f;
        for (int ci = 0; ci < 64; ++ci) {
            float xv = __shfl(x0, ci);
            const float* wr = W1T + ci * 128;
            a0 = fmaf(wr[lane], xv, a0);
            a1 = fmaf(wr[64 + lane], xv, a1);
        }
        for (int ci = 0; ci < 64; ++ci) {
            float xv = __shfl(x1, ci);
            const float* wr = W1T + (64 + ci) * 128;
            a0 = fmaf(wr[lane], xv, a0);
            a1 = fmaf(wr[64 + lane], xv, a1);
        }
        x0 = lrelu(a0 + b1f[lane]); x1 = lrelu(a1 + b1f[64 + lane]);
        a0 = 0.f; a1 = 0.f;
        for (int ci = 0; ci < 64; ++ci) {
            float xv = __shfl(x0, ci);
            const float* wr = W2T + ci * 128;
            a0 = fmaf(wr[lane], xv, a0);
            a1 = fmaf(wr[64 + lane], xv, a1);
        }
        for (int ci = 0; ci < 64; ++ci) {
            float xv = __shfl(x1, ci);
            const float* wr = W2T + (64 + ci) * 128;
            a0 = fmaf(wr[lane], xv, a0);
            a1 = fmaf(wr[64 + lane], xv, a1);
        }
        x0 = lrelu(a0 + b2f[lane]); x1 = lrelu(a1 + b2f[64 + lane]);
        a0 = 0.f; a1 = 0.f;
        for (int ci = 0; ci < 64; ++ci) {
            float xv = __shfl(x0, ci);
            const float* wr = W3T + ci * 128;
            a0 = fmaf(wr[lane], xv, a0);
            a1 = fmaf(wr[64 + lane], xv, a1);
        }
        for (int ci = 0; ci < 64; ++ci) {
            float xv = __shfl(x1, ci);
            const float* wr = W3T + (64 + ci) * 128;
            a0 = fmaf(wr[lane], xv, a0);
            a1 = fmaf(wr[64 + lane], xv, a1);
        }
        float L0 = a0 + b3f[lane], L1 = a1 + b3f[64 + lane];
        float v; int id;
        if (L0 >= L1) { v = L0; id = lane; } else { v = L1; id = 64 + lane; }
        #pragma unroll
        for (int off = 1; off < 64; off <<= 1) {
            float ov = __shfl_xor(v, off);
            int   oi = __shfl_xor(id, off);
            if (ov > v || (ov == v && oi < id)) { v = ov; id = oi; }
        }
        if (lane == 0) {
            int old = inds[n];
            if (id != old) {
                inds[n] = id;
                atomicAdd(&hist[id], 1);
                atomicSub(&hist[old], 1);
            }
        }
    }
}

// exclusive scan of histogram + build tile work-queue (64 positions per tile)
__global__ void k_scan(const int* __restrict__ hist, int* __restrict__ off,
                       int* __restrict__ cur, int* __restrict__ tiles,
                       int* __restrict__ ntt)
{
    __shared__ int s[128];
    __shared__ int s2[128];
    int t = threadIdx.x;
    int v = hist[t];
    int ntk = (v + 63) >> 6;
    s[t] = v;
    s2[t] = ntk;
    __syncthreads();
    for (int d = 1; d < 128; d <<= 1) {
        int a  = (t >= d) ? s[t - d]  : 0;
        int a2 = (t >= d) ? s2[t - d] : 0;
        __syncthreads();
        s[t] += a;
        s2[t] += a2;
        __syncthreads();
    }
    off[t] = s[t] - v;
    cur[t] = s[t] - v;
    int tb = s2[t] - ntk;
    for (int j = 0; j < ntk; ++j)
        tiles[tb + j] = (t << 16) | j;
    if (t == 127) ntt[0] = s2[127];
}

// scatter positions into buckets, block-aggregated atomics
__global__ void k_scatter(const int* __restrict__ inds, int* __restrict__ cur,
                          int* __restrict__ bucket)
{
    __shared__ int lh[128];
    __shared__ int gb[128];
    int t = threadIdx.x;
    if (t < 128) lh[t] = 0;
    __syncthreads();
    int n = blockIdx.x * 256 + t;
    int id = inds[n];
    int r = atomicAdd(&lh[id], 1);
    __syncthreads();
    if (t < 128 && lh[t] > 0) gb[t] = atomicAdd(&cur[t], lh[t]);
    __syncthreads();
    bucket[gb[id] + r] = n;
}

// bucketed per-position MLP on MFMA bf16, tile = 64 positions, bf16 gather.
__global__ __launch_bounds__(256, 4)
void k_reg(const unsigned short* __restrict__ XRB, const unsigned short* __restrict__ wbf,
           const float* __restrict__ cm2b, const float* __restrict__ cm3w,
           const float* __restrict__ cm3b, const int* __restrict__ hist,
           const int* __restrict__ off, const int* __restrict__ bucket,
           const int* __restrict__ tiles, const int* __restrict__ ntt,
           float* __restrict__ out)
{
    __shared__ __align__(16) unsigned short XP[4 * NST];
    __shared__ float red[64];
    int bid = blockIdx.x;
    if (bid >= ntt[0]) return;
    int desc = tiles[bid];
    int k = desc >> 16;
    int start = (desc & 0xffff) << 6;
    int cnt = hist[k];
    int base = off[k];
    int t = threadIdx.x;
    int lane = t & 63;
    int wv = __builtin_amdgcn_readfirstlane(t >> 6);
    const int n16 = lane & 15;
    const int quad = lane >> 4;

    // gather 64 xr rows (256 B bf16 each) -> frag-major LDS; 4 threads/row
    {
        int rs = t >> 2;                         // 0..63
        int q = t & 3;                           // = kt
        int sidx = start + rs;
        if (sidx >= cnt) sidx = cnt - 1;
        int n = bucket[base + sidx];
        const uint4* src = (const uint4*)(XRB + (unsigned)n * 128u + q * 32);
        uint4 a0 = src[0], a1 = src[1], a2 = src[2], a3 = src[3];
        unsigned db = (rs >> 4) * NST + q * 512 + (rs & 15) * 8;
        *(uint4*)&XP[db]       = a0;             // quad 0
        *(uint4*)&XP[db + 128] = a1;             // quad 1
        *(uint4*)&XP[db + 256] = a2;             // quad 2
        *(uint4*)&XP[db + 384] = a3;             // quad 3
    }
    __syncthreads();

    // B-frags: W2k^T [out][ci]
    const unsigned short* wb = wbf + UW2K + (unsigned)k * 4096u;
    bf16x8 Bf[2][4];
    #pragma unroll
    for (int nf = 0; nf < 2; ++nf)
        #pragma unroll
        for (int kt = 0; kt < 4; ++kt)
            Bf[nf][kt] = *(const bf16x8*)&wb[(nf * 16 + n16) * 128 + kt * 32 + quad * 8];

    const f32x4 vzero = {0.f, 0.f, 0.f, 0.f};
    f32x4 acc[2];
    acc[0] = vzero; acc[1] = vzero;
    #pragma unroll
    for (int kt = 0; kt < 4; ++kt) {
        bf16x8 Af = *(const bf16x8*)&XP[wv * NST + kt * 512 + lane * 8];
        #pragma unroll
        for (int nf = 0; nf < 2; ++nf)
            acc[nf] = MFMA16(Af, Bf[nf][kt], acc[nf], 0, 0, 0);
    }

    // epilogue: lane's 2 outs -> partial; shfl-reduce over 16-lane out dim
    float b2a = cm2b[k * 32 + n16], b2b = cm2b[k * 32 + 16 + n16];
    float w3a = cm3w[k * 32 + n16], w3b = cm3w[k * 32 + 16 + n16];
    #pragma unroll
    for (int r = 0; r < 4; ++r) {
        float p = lrelu(acc[0][r] + b2a) * w3a
                + lrelu(acc[1][r] + b2b) * w3b;
        p += __shfl_xor(p, 1);
        p += __shfl_xor(p, 2);
        p += __shfl_xor(p, 4);
        p += __shfl_xor(p, 8);
        if (n16 == 0)
            red[wv * 16 + quad * 4 + r] = p;
    }
    __syncthreads();
    if (t < 64 && start + t < cnt) {
        int n2 = bucket[base + start + t];
        out[n2] = ((float)k + red[t] + cm3b[k]) * (1.0f / 128.0f);
    }
}

extern "C" void kernel_launch(void* const* d_in, const int* in_sizes, int n_in,
                              void* d_out, int out_size, void* d_ws, size_t ws_size,
                              hipStream_t stream)
{
    (void)in_sizes; (void)n_in; (void)out_size; (void)ws_size;
    const float* x_in   = (const float*)d_in[0];
    const float* cl1_w  = (const float*)d_in[1];
    const float* cl1_b  = (const float*)d_in[2];
    const float* g1     = (const float*)d_in[3];
    const float* be1    = (const float*)d_in[4];
    const float* mu1    = (const float*)d_in[5];
    const float* va1    = (const float*)d_in[6];
    const float* cl2_w  = (const float*)d_in[7];
    const float* cl2_b  = (const float*)d_in[8];
    const float* cl3_w  = (const float*)d_in[9];
    const float* cl3_b  = (const float*)d_in[10];
    const float* reg1_w = (const float*)d_in[11];
    const float* reg1_b = (const float*)d_in[12];
    const float* gr     = (const float*)d_in[13];
    const float* ber    = (const float*)d_in[14];
    const float* mur    = (const float*)d_in[15];
    const float* var_   = (const float*)d_in[16];
    const float* cm2w   = (const float*)d_in[17];
    const float* cm2b   = (const float*)d_in[18];
    const float* cm3w   = (const float*)d_in[19];
    const float* cm3b   = (const float*)d_in[20];

    float* ws_f = (float*)d_ws;
    unsigned short* XRB = (unsigned short*)(ws_f + OFF_XR);
    unsigned short* wbf = (unsigned short*)(ws_f + OFF_BF16);
    int*   wsi    = (int*)(ws_f + OFF_INT);
    int*   inds   = wsi;
    int*   hist   = inds + 65536;
    int*   offb   = hist + 128;
    int*   cur    = offb + 128;
    int*   ntt    = cur + 128;
    int*   fixcnt = ntt + 4;
    int*   tiles  = fixcnt + 4;
    int*   fixlist= tiles + 1536;
    int*   bucket = fixlist + 65536;
    float* out = (float*)d_out;

    hipLaunchKernelGGL(k_prep, dim3(256), dim3(128), 0, stream,
                       cl1_w, cl1_b, g1, be1, mu1, va1, cl2_w, cl2_b, cl3_w, cl3_b,
                       reg1_w, reg1_b, gr, ber, mur, var_, cm2w, ws_f, wbf, hist, fixcnt);
    hipLaunchKernelGGL(k_fused, dim3(1024), dim3(256), 0, stream,
                       x_in, ws_f, wbf, XRB, out + 65536, inds, hist, fixcnt, fixlist);
    hipLaunchKernelGGL(k_fix, dim3(256), dim3(256), 0, stream,
                       x_in, ws_f, fixcnt, fixlist, inds, hist);
    hipLaunchKernelGGL(k_scan, dim3(1), dim3(128), 0, stream,
                       hist, offb, cur, tiles, ntt);
    hipLaunchKernelGGL(k_scatter, dim3(256), dim3(256), 0, stream, inds, cur, bucket);
    hipLaunchKernelGGL(k_reg, dim3(1536), dim3(256), 0, stream,
                       XRB, wbf, cm2b, cm3w, cm3b, hist, offb, bucket, tiles, ntt, out);
}

// Round 11
// 241.222 us; speedup vs baseline: 1.3480x; 1.3480x over previous
//
#include <hip/hip_runtime.h>
#include <math.h>

// Problem constants
#define NPOS 65536   // B*H*W = 8*1*8192
#define NCH  128
#define DELTA 0.008f // argmax top-2 gap below which we recompute in exact fp32

// ws layout (float element offsets)
#define OFF_XR   0u                       // XRB bf16 [n][128] lives here
#define OFF_W1T  8388608u                 // fixup fp32 [cin][cout]
#define OFF_W2T  (OFF_W1T + 16384u)
#define OFF_W3T  (OFF_W2T + 16384u)
#define OFF_B1F  (OFF_W3T + 16384u)
#define OFF_BRF  (OFF_B1F + 128u)
#define OFF_B2F  (OFF_BRF + 128u)
#define OFF_B3F  (OFF_B2F + 128u)         // 132 (129 used)
#define OFF_BF16 (OFF_B3F + 132u)         // ushort region
#define OFF_INT  (OFF_BF16 + 329728u)     // int region (bf16 region = 659456 ushorts)

// ushort offsets inside bf16 region
#define UW1H 0u
#define UW1L 16384u
#define UWRH 32768u
#define UWRL 49152u
#define UW2H 65536u
#define UW2L 81920u
#define UW3H 98304u      // [144][128]; row128=mask, rows129..143=0
#define UW3L 116736u
#define UW2K 135168u     // cm2w bf16 transposed [k][out][ci] : 524288 -> end 659456

// frag-major LDS: [mg][kt][lane][8 ushorts], +32-ushort pad per mg
#define NST 2080         // 4*512 + 32

typedef short bf16x8 __attribute__((ext_vector_type(8)));
typedef float f32x4 __attribute__((ext_vector_type(4)));
#define MFMA16 __builtin_amdgcn_mfma_f32_16x16x32_bf16

__device__ __forceinline__ float lrelu(float v) { return v >= 0.0f ? v : 0.01f * v; }
__device__ __forceinline__ unsigned short f2bf(float f) {
    unsigned u = __float_as_uint(f);
    return (unsigned short)((u + 0x7fffu + ((u >> 16) & 1u)) >> 16);
}
__device__ __forceinline__ float bf2f(unsigned short h) {
    return __uint_as_float(((unsigned)h) << 16);
}
__device__ __forceinline__ unsigned long long pack4(unsigned short a, unsigned short b,
                                                    unsigned short c, unsigned short d) {
    return (unsigned long long)a | ((unsigned long long)b << 16)
         | ((unsigned long long)c << 32) | ((unsigned long long)d << 48);
}

// ---------------------------------------------------------------------------
// prep: blocks 0..127: fold BN, fp32 fixup tables, bf16 hi/lo planes, biases.
//       blocks 128..255: cm2w -> bf16 transposed [k][out][ci] via LDS tile.
// ---------------------------------------------------------------------------
__global__ void k_prep(const float* __restrict__ cl1_w, const float* __restrict__ cl1_b,
                       const float* __restrict__ g1, const float* __restrict__ be1,
                       const float* __restrict__ mu1, const float* __restrict__ va1,
                       const float* __restrict__ cl2_w, const float* __restrict__ cl2_b,
                       const float* __restrict__ cl3_w, const float* __restrict__ cl3_b,
                       const float* __restrict__ reg1_w, const float* __restrict__ reg1_b,
                       const float* __restrict__ gr, const float* __restrict__ ber,
                       const float* __restrict__ mur, const float* __restrict__ var_,
                       const float* __restrict__ cm2w,
                       float* __restrict__ ws_f, unsigned short* __restrict__ wbf,
                       int* __restrict__ hist, int* __restrict__ fixcnt)
{
    const int bid = blockIdx.x;
    const int t = threadIdx.x;
    if (bid >= 128) {                       // cm2w transpose, one k per block
        __shared__ float tl[32 * 132];      // [o][ci]
        int k = bid - 128;
        #pragma unroll
        for (int i = 0; i < 32; ++i) {
            float v = cm2w[(unsigned)k * 4096u + i * 128 + t];  // coalesced
            int ci = i * 4 + (t >> 5), o = t & 31;
            tl[o * 132 + ci] = v;
        }
        __syncthreads();
        #pragma unroll
        for (int i = 0; i < 32; ++i)
            wbf[UW2K + (unsigned)k * 4096u + i * 128 + t] = f2bf(tl[i * 132 + t]);
        return;
    }
    int tid = bid * 128 + t;                // 16384 threads
    int cin = tid >> 7, cout = tid & 127;
    float s1 = g1[cout] / sqrtf(va1[cout] + 1e-5f);
    float sr = gr[cout] / sqrtf(var_[cout] + 1e-5f);
    float w1 = cl1_w[cout * 128 + cin] * s1;
    float wr = reg1_w[cout * 128 + cin] * sr;
    float w2 = cl2_w[cout * 128 + cin];
    float w3 = cl3_w[cout * 128 + cin];
    ws_f[OFF_W1T + tid] = w1;
    ws_f[OFF_W2T + tid] = w2;
    ws_f[OFF_W3T + tid] = w3;
    int j = cout * 128 + cin;
    unsigned short h;
    h = f2bf(w1); wbf[UW1H + j] = h; wbf[UW1L + j] = f2bf(w1 - bf2f(h));
    h = f2bf(wr); wbf[UWRH + j] = h; wbf[UWRL + j] = f2bf(wr - bf2f(h));
    h = f2bf(w2); wbf[UW2H + j] = h; wbf[UW2L + j] = f2bf(w2 - bf2f(h));
    h = f2bf(w3); wbf[UW3H + j] = h; wbf[UW3L + j] = f2bf(w3 - bf2f(h));
    if (tid < 2048) {               // W3 rows 128..143: mask row then zeros
        int r = tid >> 7, ci = tid & 127;
        float v = (r == 0) ? cl3_w[128 * 128 + ci] : 0.0f;
        int jj = (128 + r) * 128 + ci;
        h = f2bf(v); wbf[UW3H + jj] = h; wbf[UW3L + jj] = f2bf(v - bf2f(h));
    }
    if (tid < 128) {
        float s1b = g1[tid] / sqrtf(va1[tid] + 1e-5f);
        float srb = gr[tid] / sqrtf(var_[tid] + 1e-5f);
        ws_f[OFF_B1F + tid] = cl1_b[tid] * s1b + be1[tid] - mu1[tid] * s1b;
        ws_f[OFF_BRF + tid] = reg1_b[tid] * srb + ber[tid] - mur[tid] * srb;
        ws_f[OFF_B2F + tid] = cl2_b[tid];
        hist[tid] = 0;
    }
    if (tid < 129) ws_f[OFF_B3F + tid] = cl3_b[tid];
    if (tid == 0) fixcnt[0] = 0;
}

// ---------------------------------------------------------------------------
// FUSED pipeline on MFMA — R10 structure with ONE change: NO hist atomics in
// the epilogue (hist moves back to the separate block-aggregated k_hist).
// xr stored bf16 (ushort4), as in R10.
// ---------------------------------------------------------------------------
__global__ __launch_bounds__(256, 2)
void k_fused(const float* __restrict__ X, const float* __restrict__ wsf,
             const unsigned short* __restrict__ wbf,
             unsigned short* __restrict__ XRB, float* __restrict__ out_mask,
             int* __restrict__ inds, int* __restrict__ fixcnt,
             int* __restrict__ fixlist)
{
    __shared__ __align__(16) unsigned short XBh[64 * 136];
    __shared__ __align__(16) unsigned short XBl[64 * 136];
    __shared__ float sm1[4 * 64];
    __shared__ float sm2[4 * 64];
    __shared__ int   si1[4 * 64];

    const int t = threadIdx.x;
    const int lane = t & 63;
    const int cl16 = lane & 15;           // col / n within fragment
    const int q8 = (lane >> 4) * 8;       // k-offset within fragment
    const int q4 = (lane >> 4) * 4;       // row-offset within D fragment
    const int wv = __builtin_amdgcn_readfirstlane(t >> 6);
    const unsigned nt64 = blockIdx.x * 64u;
    const unsigned base = nt64 + (nt64 >> 13) * 1040384u;   // b*1048576 + w0

    const unsigned short* W1H = wbf + UW1H; const unsigned short* W1L = wbf + UW1L;
    const unsigned short* WRH = wbf + UWRH; const unsigned short* WRL = wbf + UWRL;
    const unsigned short* W2H = wbf + UW2H; const unsigned short* W2L = wbf + UW2L;
    const unsigned short* W3H = wbf + UW3H; const unsigned short* W3L = wbf + UW3L;
    const float* b1f = wsf + OFF_B1F;
    const float* brf = wsf + OFF_BRF;
    const float* b2f = wsf + OFF_B2F;
    const float* b3f = wsf + OFF_B3F;

    const f32x4 vzero = {0.f, 0.f, 0.f, 0.f};

    // ---- stage x tile -> bf16 hi/lo planes [pos][cin] ----
    {
        const int pos = t & 63, cig = t >> 6;      // cig: 0..3
        #pragma unroll
        for (int l = 0; l < 8; ++l) {
            int ci0 = cig * 32 + l * 4;
            float v0 = X[base + (unsigned)(ci0 + 0) * 8192u + pos];
            float v1 = X[base + (unsigned)(ci0 + 1) * 8192u + pos];
            float v2 = X[base + (unsigned)(ci0 + 2) * 8192u + pos];
            float v3 = X[base + (unsigned)(ci0 + 3) * 8192u + pos];
            unsigned short h0 = f2bf(v0), h1 = f2bf(v1), h2 = f2bf(v2), h3 = f2bf(v3);
            unsigned long long ph = pack4(h0, h1, h2, h3);
            unsigned long long pl = pack4(f2bf(v0 - bf2f(h0)), f2bf(v1 - bf2f(h1)),
                                          f2bf(v2 - bf2f(h2)), f2bf(v3 - bf2f(h3)));
            *(unsigned long long*)&XBh[pos * 136 + ci0] = ph;
            *(unsigned long long*)&XBl[pos * 136 + ci0] = pl;
        }
    }
    __syncthreads();

    // ---- P1: y1 (W1) and xr (WR) in one pass over B frags ----
    f32x4 aY[2][4], aR[2][4];
    #pragma unroll
    for (int m = 0; m < 2; ++m)
        #pragma unroll
        for (int n = 0; n < 4; ++n) { aY[m][n] = vzero; aR[m][n] = vzero; }
    #pragma unroll
    for (int kt = 0; kt < 4; ++kt) {
        bf16x8 Bh[4], Bl[4];
        #pragma unroll
        for (int n = 0; n < 4; ++n) {
            int bo = (n * 16 + cl16) * 136 + kt * 32 + q8;
            Bh[n] = *(const bf16x8*)&XBh[bo];
            Bl[n] = *(const bf16x8*)&XBl[bo];
        }
        #pragma unroll
        for (int m = 0; m < 2; ++m) {
            int ao = (wv * 32 + m * 16 + cl16) * 128 + kt * 32 + q8;
            bf16x8 a1h = *(const bf16x8*)&W1H[ao], a1l = *(const bf16x8*)&W1L[ao];
            bf16x8 arh = *(const bf16x8*)&WRH[ao], arl = *(const bf16x8*)&WRL[ao];
            #pragma unroll
            for (int n = 0; n < 4; ++n) {
                aY[m][n] = MFMA16(a1h, Bl[n], aY[m][n], 0, 0, 0);
                aY[m][n] = MFMA16(a1l, Bh[n], aY[m][n], 0, 0, 0);
                aY[m][n] = MFMA16(a1h, Bh[n], aY[m][n], 0, 0, 0);
                aR[m][n] = MFMA16(arh, Bl[n], aR[m][n], 0, 0, 0);
                aR[m][n] = MFMA16(arl, Bh[n], aR[m][n], 0, 0, 0);
                aR[m][n] = MFMA16(arh, Bh[n], aR[m][n], 0, 0, 0);
            }
        }
    }
    __syncthreads();                       // all P1 reads of XB done

    // xr epilogue -> global XRB[n][c] bf16 (ushort4; 16 rows x 32B contiguous)
    {
        #pragma unroll
        for (int m = 0; m < 2; ++m) {
            int cb = wv * 32 + m * 16 + q4;
            float br0 = brf[cb], br1 = brf[cb + 1], br2 = brf[cb + 2], br3 = brf[cb + 3];
            #pragma unroll
            for (int n = 0; n < 4; ++n) {
                unsigned pb = (nt64 + n * 16 + cl16) * 128u + cb;
                ushort4 xo;
                xo.x = f2bf(lrelu(aR[m][n][0] + br0));
                xo.y = f2bf(lrelu(aR[m][n][1] + br1));
                xo.z = f2bf(lrelu(aR[m][n][2] + br2));
                xo.w = f2bf(lrelu(aR[m][n][3] + br3));
                *(ushort4*)&XRB[pb] = xo;
            }
        }
    }
    // y1 epilogue -> XB planes
    {
        #pragma unroll
        for (int m = 0; m < 2; ++m) {
            int cb = wv * 32 + m * 16 + q4;
            float b0 = b1f[cb], b1 = b1f[cb + 1], b2 = b1f[cb + 2], b3 = b1f[cb + 3];
            #pragma unroll
            for (int n = 0; n < 4; ++n) {
                float v0 = lrelu(aY[m][n][0] + b0), v1 = lrelu(aY[m][n][1] + b1);
                float v2 = lrelu(aY[m][n][2] + b2), v3 = lrelu(aY[m][n][3] + b3);
                unsigned short h0 = f2bf(v0), h1 = f2bf(v1), h2 = f2bf(v2), h3 = f2bf(v3);
                unsigned long long ph = pack4(h0, h1, h2, h3);
                unsigned long long pl = pack4(f2bf(v0 - bf2f(h0)), f2bf(v1 - bf2f(h1)),
                                              f2bf(v2 - bf2f(h2)), f2bf(v3 - bf2f(h3)));
                int idx = (n * 16 + cl16) * 136 + cb;
                *(unsigned long long*)&XBh[idx] = ph;
                *(unsigned long long*)&XBl[idx] = pl;
            }
        }
    }
    __syncthreads();

    // ---- P2: y2 = lrelu(W2 y1 + b2) ----
    f32x4 aZ[2][4];
    #pragma unroll
    for (int m = 0; m < 2; ++m)
        #pragma unroll
        for (int n = 0; n < 4; ++n) aZ[m][n] = vzero;
    #pragma unroll
    for (int kt = 0; kt < 4; ++kt) {
        bf16x8 Bh[4], Bl[4];
        #pragma unroll
        for (int n = 0; n < 4; ++n) {
            int bo = (n * 16 + cl16) * 136 + kt * 32 + q8;
            Bh[n] = *(const bf16x8*)&XBh[bo];
            Bl[n] = *(const bf16x8*)&XBl[bo];
        }
        #pragma unroll
        for (int m = 0; m < 2; ++m) {
            int ao = (wv * 32 + m * 16 + cl16) * 128 + kt * 32 + q8;
            bf16x8 ah = *(const bf16x8*)&W2H[ao], al = *(const bf16x8*)&W2L[ao];
            #pragma unroll
            for (int n = 0; n < 4; ++n) {
                aZ[m][n] = MFMA16(ah, Bl[n], aZ[m][n], 0, 0, 0);
                aZ[m][n] = MFMA16(al, Bh[n], aZ[m][n], 0, 0, 0);
                aZ[m][n] = MFMA16(ah, Bh[n], aZ[m][n], 0, 0, 0);
            }
        }
    }
    __syncthreads();
    {
        #pragma unroll
        for (int m = 0; m < 2; ++m) {
            int cb = wv * 32 + m * 16 + q4;
            float b0 = b2f[cb], b1 = b2f[cb + 1], b2 = b2f[cb + 2], b3 = b2f[cb + 3];
            #pragma unroll
            for (int n = 0; n < 4; ++n) {
                float v0 = lrelu(aZ[m][n][0] + b0), v1 = lrelu(aZ[m][n][1] + b1);
                float v2 = lrelu(aZ[m][n][2] + b2), v3 = lrelu(aZ[m][n][3] + b3);
                unsigned short h0 = f2bf(v0), h1 = f2bf(v1), h2 = f2bf(v2), h3 = f2bf(v3);
                unsigned long long ph = pack4(h0, h1, h2, h3);
                unsigned long long pl = pack4(f2bf(v0 - bf2f(h0)), f2bf(v1 - bf2f(h1)),
                                              f2bf(v2 - bf2f(h2)), f2bf(v3 - bf2f(h3)));
                int idx = (n * 16 + cl16) * 136 + cb;
                *(unsigned long long*)&XBh[idx] = ph;
                *(unsigned long long*)&XBl[idx] = pl;
            }
        }
    }
    __syncthreads();

    // ---- P3: logits (+ mask row on wave 3) ----
    f32x4 aL[2][4], aM[4];
    #pragma unroll
    for (int m = 0; m < 2; ++m)
        #pragma unroll
        for (int n = 0; n < 4; ++n) aL[m][n] = vzero;
    #pragma unroll
    for (int n = 0; n < 4; ++n) aM[n] = vzero;
    #pragma unroll
    for (int kt = 0; kt < 4; ++kt) {
        bf16x8 Bh[4], Bl[4];
        #pragma unroll
        for (int n = 0; n < 4; ++n) {
            int bo = (n * 16 + cl16) * 136 + kt * 32 + q8;
            Bh[n] = *(const bf16x8*)&XBh[bo];
            Bl[n] = *(const bf16x8*)&XBl[bo];
        }
        #pragma unroll
        for (int m = 0; m < 2; ++m) {
            int ao = (wv * 32 + m * 16 + cl16) * 128 + kt * 32 + q8;
            bf16x8 ah = *(const bf16x8*)&W3H[ao], al = *(const bf16x8*)&W3L[ao];
            #pragma unroll
            for (int n = 0; n < 4; ++n) {
                aL[m][n] = MFMA16(ah, Bl[n], aL[m][n], 0, 0, 0);
                aL[m][n] = MFMA16(al, Bh[n], aL[m][n], 0, 0, 0);
                aL[m][n] = MFMA16(ah, Bh[n], aL[m][n], 0, 0, 0);
            }
        }
        if (wv == 3) {   // mask row block (rows 128..143, only row 128 used)
            int ao = (128 + cl16) * 128 + kt * 32 + q8;
            bf16x8 ah = *(const bf16x8*)&W3H[ao], al = *(const bf16x8*)&W3L[ao];
            #pragma unroll
            for (int n = 0; n < 4; ++n) {
                aM[n] = MFMA16(ah, Bl[n], aM[n], 0, 0, 0);
                aM[n] = MFMA16(al, Bh[n], aM[n], 0, 0, 0);
                aM[n] = MFMA16(ah, Bh[n], aM[n], 0, 0, 0);
            }
        }
    }

    // per-lane top-2 over its 8 couts (ascending cout = numpy first-tie rule)
    {
        float bb[2][4];
        #pragma unroll
        for (int m = 0; m < 2; ++m) {
            int cb = wv * 32 + m * 16 + q4;
            bb[m][0] = b3f[cb]; bb[m][1] = b3f[cb + 1];
            bb[m][2] = b3f[cb + 2]; bb[m][3] = b3f[cb + 3];
        }
        float m1[4], m2[4]; int i1[4];
        #pragma unroll
        for (int n = 0; n < 4; ++n) {
            m1[n] = -1e30f; m2[n] = -1e30f; i1[n] = 0;
            #pragma unroll
            for (int m = 0; m < 2; ++m) {
                int cb = wv * 32 + m * 16 + q4;
                #pragma unroll
                for (int r = 0; r < 4; ++r) {
                    float v = aL[m][n][r] + bb[m][r];
                    if (v > m1[n]) { m2[n] = m1[n]; m1[n] = v; i1[n] = cb + r; }
                    else if (v > m2[n]) m2[n] = v;
                }
            }
        }
        #pragma unroll
        for (int off = 16; off <= 32; off <<= 1) {
            #pragma unroll
            for (int n = 0; n < 4; ++n) {
                float om1 = __shfl_xor(m1[n], off);
                float om2 = __shfl_xor(m2[n], off);
                int   oi1 = __shfl_xor(i1[n], off);
                if (om1 > m1[n] || (om1 == m1[n] && oi1 < i1[n])) {
                    m2[n] = fmaxf(m1[n], om2); m1[n] = om1; i1[n] = oi1;
                } else {
                    m2[n] = fmaxf(m2[n], om1);
                }
            }
        }
        if ((lane >> 4) == 0) {
            #pragma unroll
            for (int n = 0; n < 4; ++n) {
                sm1[wv * 64 + n * 16 + cl16] = m1[n];
                sm2[wv * 64 + n * 16 + cl16] = m2[n];
                si1[wv * 64 + n * 16 + cl16] = i1[n];
            }
        }
    }
    if (wv == 3 && (lane >> 4) == 0) {
        float mb = b3f[128];
        #pragma unroll
        for (int n = 0; n < 4; ++n)
            out_mask[nt64 + n * 16 + cl16] = lrelu(aM[n][0] + mb);
    }
    __syncthreads();
    if (t < 64) {
        float m1 = sm1[t], m2 = sm2[t];
        int i1 = si1[t];
        #pragma unroll
        for (int w = 1; w < 4; ++w) {     // ascending wv = ascending cout
            float v1 = sm1[w * 64 + t];
            float v2 = sm2[w * 64 + t];
            int   vi = si1[w * 64 + t];
            if (v1 > m1) { m2 = fmaxf(m1, v2); m1 = v1; i1 = vi; }
            else         { m2 = fmaxf(m2, v1); }
        }
        int n = nt64 + t;
        inds[n] = i1;
        if (m1 - m2 < DELTA) {
            int slot = atomicAdd(fixcnt, 1);
            fixlist[slot] = n;
        }
    }
}

// ---------------------------------------------------------------------------
// fixup: ONE WAVE per flagged position, exact fp32, lane-coalesced weights.
// Updates inds only (hist built afterwards by k_hist).
// ---------------------------------------------------------------------------
__global__ __launch_bounds__(256, 4)
void k_fix(const float* __restrict__ X, const float* __restrict__ wsf,
           const int* __restrict__ fixcnt, const int* __restrict__ fixlist,
           int* __restrict__ inds)
{
    const int cnt = fixcnt[0];
    const int t = threadIdx.x;
    const int lane = t & 63;
    const int wv = t >> 6;
    const float* W1T = wsf + OFF_W1T;
    const float* W2T = wsf + OFF_W2T;
    const float* W3T = wsf + OFF_W3T;
    const float* b1f = wsf + OFF_B1F;
    const float* b2f = wsf + OFF_B2F;
    const float* b3f = wsf + OFF_B3F;

    for (int idx = blockIdx.x * 4 + wv; idx < cnt; idx += 1024) {
        int n = fixlist[idx];
        const float* xb = X + (unsigned)(n >> 13) * 1048576u + (unsigned)(n & 8191);
        float x0 = xb[(unsigned)lane * 8192u];
        float x1 = xb[(unsigned)(64 + lane) * 8192u];
        float a0, a1;
        a0 = 0.f; a1 = 0.f;
        for (int ci = 0; ci < 64; ++ci) {
            float xv = __shfl(x0, ci);
            const float* wr = W1T + ci * 128;
            a0 = fmaf(wr[lane], xv, a0);
            a1 = fmaf(wr[64 + lane], xv, a1);
        }
        for (int ci = 0; ci < 64; ++ci) {
            float xv = __shfl(x1, ci);
            const float* wr = W1T + (64 + ci) * 128;
            a0 = fmaf(wr[lane], xv, a0);
            a1 = fmaf(wr[64 + lane], xv, a1);
        }
        x0 = lrelu(a0 + b1f[lane]); x1 = lrelu(a1 + b1f[64 + lane]);
        a0 = 0.f; a1 = 0.f;
        for (int ci = 0; ci < 64; ++ci) {
            float xv = __shfl(x0, ci);
            const float* wr = W2T + ci * 128;
            a0 = fmaf(wr[lane], xv, a0);
            a1 = fmaf(wr[64 + lane], xv, a1);
        }
        for (int ci = 0; ci < 64; ++ci) {
            float xv = __shfl(x1, ci);
            const float* wr = W2T + (64 + ci) * 128;
            a0 = fmaf(wr[lane], xv, a0);
            a1 = fmaf(wr[64 + lane], xv, a1);
        }
        x0 = lrelu(a0 + b2f[lane]); x1 = lrelu(a1 + b2f[64 + lane]);
        a0 = 0.f; a1 = 0.f;
        for (int ci = 0; ci < 64; ++ci) {
            float xv = __shfl(x0, ci);
            const float* wr = W3T + ci * 128;
            a0 = fmaf(wr[lane], xv, a0);
            a1 = fmaf(wr[64 + lane], xv, a1);
        }
        for (int ci = 0; ci < 64; ++ci) {
            float xv = __shfl(x1, ci);
            const float* wr = W3T + (64 + ci) * 128;
            a0 = fmaf(wr[lane], xv, a0);
            a1 = fmaf(wr[64 + lane], xv, a1);
        }
        float L0 = a0 + b3f[lane], L1 = a1 + b3f[64 + lane];
        float v; int id;
        if (L0 >= L1) { v = L0; id = lane; } else { v = L1; id = 64 + lane; }
        #pragma unroll
        for (int off = 1; off < 64; off <<= 1) {
            float ov = __shfl_xor(v, off);
            int   oi = __shfl_xor(id, off);
            if (ov > v || (ov == v && oi < id)) { v = ov; id = oi; }
        }
        if (lane == 0) inds[n] = id;
    }
}

// histogram from final inds (block-aggregated atomics) — R9 measured path
__global__ void k_hist(const int* __restrict__ inds, int* __restrict__ hist)
{
    __shared__ int lh[128];
    int t = threadIdx.x;
    if (t < 128) lh[t] = 0;
    __syncthreads();
    atomicAdd(&lh[inds[blockIdx.x * 256 + t]], 1);
    __syncthreads();
    if (t < 128 && lh[t] > 0) atomicAdd(&hist[t], lh[t]);
}

// exclusive scan of histogram + build tile work-queue (64 positions per tile)
__global__ void k_scan(const int* __restrict__ hist, int* __restrict__ off,
                       int* __restrict__ cur, int* __restrict__ tiles,
                       int* __restrict__ ntt)
{
    __shared__ int s[128];
    __shared__ int s2[128];
    int t = threadIdx.x;
    int v = hist[t];
    int ntk = (v + 63) >> 6;
    s[t] = v;
    s2[t] = ntk;
    __syncthreads();
    for (int d = 1; d < 128; d <<= 1) {
        int a  = (t >= d) ? s[t - d]  : 0;
        int a2 = (t >= d) ? s2[t - d] : 0;
        __syncthreads();
        s[t] += a;
        s2[t] += a2;
        __syncthreads();
    }
    off[t] = s[t] - v;
    cur[t] = s[t] - v;
    int tb = s2[t] - ntk;
    for (int j = 0; j < ntk; ++j)
        tiles[tb + j] = (t << 16) | j;
    if (t == 127) ntt[0] = s2[127];
}

// scatter positions into buckets, block-aggregated atomics
__global__ void k_scatter(const int* __restrict__ inds, int* __restrict__ cur,
                          int* __restrict__ bucket)
{
    __shared__ int lh[128];
    __shared__ int gb[128];
    int t = threadIdx.x;
    if (t < 128) lh[t] = 0;
    __syncthreads();
    int n = blockIdx.x * 256 + t;
    int id = inds[n];
    int r = atomicAdd(&lh[id], 1);
    __syncthreads();
    if (t < 128 && lh[t] > 0) gb[t] = atomicAdd(&cur[t], lh[t]);
    __syncthreads();
    bucket[gb[id] + r] = n;
}

// bucketed per-position MLP on MFMA bf16, tile = 64 positions, bf16 gather.
__global__ __launch_bounds__(256, 4)
void k_reg(const unsigned short* __restrict__ XRB, const unsigned short* __restrict__ wbf,
           const float* __restrict__ cm2b, const float* __restrict__ cm3w,
           const float* __restrict__ cm3b, const int* __restrict__ hist,
           const int* __restrict__ off, const int* __restrict__ bucket,
           const int* __restrict__ tiles, const int* __restrict__ ntt,
           float* __restrict__ out)
{
    __shared__ __align__(16) unsigned short XP[4 * NST];
    __shared__ float red[64];
    int bid = blockIdx.x;
    if (bid >= ntt[0]) return;
    int desc = tiles[bid];
    int k = desc >> 16;
    int start = (desc & 0xffff) << 6;
    int cnt = hist[k];
    int base = off[k];
    int t = threadIdx.x;
    int lane = t & 63;
    int wv = __builtin_amdgcn_readfirstlane(t >> 6);
    const int n16 = lane & 15;
    const int quad = lane >> 4;

    // gather 64 xr rows (256 B bf16 each) -> frag-major LDS; 4 threads/row
    {
        int rs = t >> 2;                         // 0..63
        int q = t & 3;                           // = kt
        int sidx = start + rs;
        if (sidx >= cnt) sidx = cnt - 1;
        int n = bucket[base + sidx];
        const uint4* src = (const uint4*)(XRB + (unsigned)n * 128u + q * 32);
        uint4 a0 = src[0], a1 = src[1], a2 = src[2], a3 = src[3];
        unsigned db = (rs >> 4) * NST + q * 512 + (rs & 15) * 8;
        *(uint4*)&XP[db]       = a0;             // quad 0
        *(uint4*)&XP[db + 128] = a1;             // quad 1
        *(uint4*)&XP[db + 256] = a2;             // quad 2
        *(uint4*)&XP[db + 384] = a3;             // quad 3
    }
    __syncthreads();

    // B-frags: W2k^T [out][ci]
    const unsigned short* wb = wbf + UW2K + (unsigned)k * 4096u;
    bf16x8 Bf[2][4];
    #pragma unroll
    for (int nf = 0; nf < 2; ++nf)
        #pragma unroll
        for (int kt = 0; kt < 4; ++kt)
            Bf[nf][kt] = *(const bf16x8*)&wb[(nf * 16 + n16) * 128 + kt * 32 + quad * 8];

    const f32x4 vzero = {0.f, 0.f, 0.f, 0.f};
    f32x4 acc[2];
    acc[0] = vzero; acc[1] = vzero;
    #pragma unroll
    for (int kt = 0; kt < 4; ++kt) {
        bf16x8 Af = *(const bf16x8*)&XP[wv * NST + kt * 512 + lane * 8];
        #pragma unroll
        for (int nf = 0; nf < 2; ++nf)
            acc[nf] = MFMA16(Af, Bf[nf][kt], acc[nf], 0, 0, 0);
    }

    // epilogue: lane's 2 outs -> partial; shfl-reduce over 16-lane out dim
    float b2a = cm2b[k * 32 + n16], b2b = cm2b[k * 32 + 16 + n16];
    float w3a = cm3w[k * 32 + n16], w3b = cm3w[k * 32 + 16 + n16];
    #pragma unroll
    for (int r = 0; r < 4; ++r) {
        float p = lrelu(acc[0][r] + b2a) * w3a
                + lrelu(acc[1][r] + b2b) * w3b;
        p += __shfl_xor(p, 1);
        p += __shfl_xor(p, 2);
        p += __shfl_xor(p, 4);
        p += __shfl_xor(p, 8);
        if (n16 == 0)
            red[wv * 16 + quad * 4 + r] = p;
    }
    __syncthreads();
    if (t < 64 && start + t < cnt) {
        int n2 = bucket[base + start + t];
        out[n2] = ((float)k + red[t] + cm3b[k]) * (1.0f / 128.0f);
    }
}

extern "C" void kernel_launch(void* const* d_in, const int* in_sizes, int n_in,
                              void* d_out, int out_size, void* d_ws, size_t ws_size,
                              hipStream_t stream)
{
    (void)in_sizes; (void)n_in; (void)out_size; (void)ws_size;
    const float* x_in   = (const float*)d_in[0];
    const float* cl1_w  = (const float*)d_in[1];
    const float* cl1_b  = (const float*)d_in[2];
    const float* g1     = (const float*)d_in[3];
    const float* be1    = (const float*)d_in[4];
    const float* mu1    = (const float*)d_in[5];
    const float* va1    = (const float*)d_in[6];
    const float* cl2_w  = (const float*)d_in[7];
    const float* cl2_b  = (const float*)d_in[8];
    const float* cl3_w  = (const float*)d_in[9];
    const float* cl3_b  = (const float*)d_in[10];
    const float* reg1_w = (const float*)d_in[11];
    const float* reg1_b = (const float*)d_in[12];
    const float* gr     = (const float*)d_in[13];
    const float* ber    = (const float*)d_in[14];
    const float* mur    = (const float*)d_in[15];
    const float* var_   = (const float*)d_in[16];
    const float* cm2w   = (const float*)d_in[17];
    const float* cm2b   = (const float*)d_in[18];
    const float* cm3w   = (const float*)d_in[19];
    const float* cm3b   = (const float*)d_in[20];

    float* ws_f = (float*)d_ws;
    unsigned short* XRB = (unsigned short*)(ws_f + OFF_XR);
    unsigned short* wbf = (unsigned short*)(ws_f + OFF_BF16);
    int*   wsi    = (int*)(ws_f + OFF_INT);
    int*   inds   = wsi;
    int*   hist   = inds + 65536;
    int*   offb   = hist + 128;
    int*   cur    = offb + 128;
    int*   ntt    = cur + 128;
    int*   fixcnt = ntt + 4;
    int*   tiles  = fixcnt + 4;
    int*   fixlist= tiles + 1536;
    int*   bucket = fixlist + 65536;
    float* out = (float*)d_out;

    hipLaunchKernelGGL(k_prep, dim3(256), dim3(128), 0, stream,
                       cl1_w, cl1_b, g1, be1, mu1, va1, cl2_w, cl2_b, cl3_w, cl3_b,
                       reg1_w, reg1_b, gr, ber, mur, var_, cm2w, ws_f, wbf, hist, fixcnt);
    hipLaunchKernelGGL(k_fused, dim3(1024), dim3(256), 0, stream,
                       x_in, ws_f, wbf, XRB, out + 65536, inds, fixcnt, fixlist);
    hipLaunchKernelGGL(k_fix, dim3(256), dim3(256), 0, stream,
                       x_in, ws_f, fixcnt, fixlist, inds);
    hipLaunchKernelGGL(k_hist, dim3(256), dim3(256), 0, stream, inds, hist);
    hipLaunchKernelGGL(k_scan, dim3(1), dim3(128), 0, stream,
                       hist, offb, cur, tiles, ntt);
    hipLaunchKernelGGL(k_scatter, dim3(256), dim3(256), 0, stream, inds, cur, bucket);
    hipLaunchKernelGGL(k_reg, dim3(1536), dim3(256), 0, stream,
                       XRB, wbf, cm2b, cm3w, cm3b, hist, offb, bucket, tiles, ntt, out);
}

// Round 12
// 232.760 us; speedup vs baseline: 1.3970x; 1.0364x over previous
//
#include <hip/hip_runtime.h>
#include <math.h>

// Problem constants
#define NPOS 65536   // B*H*W = 8*1*8192
#define NCH  128
#define DELTA 0.008f // argmax top-2 gap below which we recompute in exact fp32
#define HPAD 16      // ints per histogram bin slot (64 B = 1 cache line per bin)

// ws layout (float element offsets)
#define OFF_XR   0u                       // XRB bf16 [n][128] lives here
#define OFF_W1T  8388608u                 // fixup fp32 [cin][cout]
#define OFF_W2T  (OFF_W1T + 16384u)
#define OFF_W3T  (OFF_W2T + 16384u)
#define OFF_B1F  (OFF_W3T + 16384u)
#define OFF_BRF  (OFF_B1F + 128u)
#define OFF_B2F  (OFF_BRF + 128u)
#define OFF_B3F  (OFF_B2F + 128u)         // 132 (129 used)
#define OFF_BF16 (OFF_B3F + 132u)         // ushort region
#define OFF_INT  (OFF_BF16 + 329728u)     // int region (bf16 region = 659456 ushorts)

// ushort offsets inside bf16 region
#define UW1H 0u
#define UW1L 16384u
#define UWRH 32768u
#define UWRL 49152u
#define UW2H 65536u
#define UW2L 81920u
#define UW3H 98304u      // [144][128]; row128=mask, rows129..143=0
#define UW3L 116736u
#define UW2K 135168u     // cm2w bf16 transposed [k][out][ci] : 524288 -> end 659456

// frag-major LDS: [mg][kt][lane][8 ushorts], +32-ushort pad per mg
#define NST 2080         // 4*512 + 32

typedef short bf16x8 __attribute__((ext_vector_type(8)));
typedef float f32x4 __attribute__((ext_vector_type(4)));
#define MFMA16 __builtin_amdgcn_mfma_f32_16x16x32_bf16

__device__ __forceinline__ float lrelu(float v) { return v >= 0.0f ? v : 0.01f * v; }
__device__ __forceinline__ unsigned short f2bf(float f) {
    unsigned u = __float_as_uint(f);
    return (unsigned short)((u + 0x7fffu + ((u >> 16) & 1u)) >> 16);
}
__device__ __forceinline__ float bf2f(unsigned short h) {
    return __uint_as_float(((unsigned)h) << 16);
}
__device__ __forceinline__ unsigned long long pack4(unsigned short a, unsigned short b,
                                                    unsigned short c, unsigned short d) {
    return (unsigned long long)a | ((unsigned long long)b << 16)
         | ((unsigned long long)c << 32) | ((unsigned long long)d << 48);
}

// ---------------------------------------------------------------------------
// prep: blocks 0..127: fold BN, fp32 fixup tables, bf16 hi/lo planes, biases.
//       blocks 128..255: cm2w -> bf16 transposed [k][out][ci] via LDS tile.
// ---------------------------------------------------------------------------
__global__ void k_prep(const float* __restrict__ cl1_w, const float* __restrict__ cl1_b,
                       const float* __restrict__ g1, const float* __restrict__ be1,
                       const float* __restrict__ mu1, const float* __restrict__ va1,
                       const float* __restrict__ cl2_w, const float* __restrict__ cl2_b,
                       const float* __restrict__ cl3_w, const float* __restrict__ cl3_b,
                       const float* __restrict__ reg1_w, const float* __restrict__ reg1_b,
                       const float* __restrict__ gr, const float* __restrict__ ber,
                       const float* __restrict__ mur, const float* __restrict__ var_,
                       const float* __restrict__ cm2w,
                       float* __restrict__ ws_f, unsigned short* __restrict__ wbf,
                       int* __restrict__ hist, int* __restrict__ fixcnt)
{
    const int bid = blockIdx.x;
    const int t = threadIdx.x;
    if (bid >= 128) {                       // cm2w transpose, one k per block
        __shared__ float tl[32 * 132];      // [o][ci]
        int k = bid - 128;
        #pragma unroll
        for (int i = 0; i < 32; ++i) {
            float v = cm2w[(unsigned)k * 4096u + i * 128 + t];  // coalesced
            int ci = i * 4 + (t >> 5), o = t & 31;
            tl[o * 132 + ci] = v;
        }
        __syncthreads();
        #pragma unroll
        for (int i = 0; i < 32; ++i)
            wbf[UW2K + (unsigned)k * 4096u + i * 128 + t] = f2bf(tl[i * 132 + t]);
        return;
    }
    int tid = bid * 128 + t;                // 16384 threads
    int cin = tid >> 7, cout = tid & 127;
    float s1 = g1[cout] / sqrtf(va1[cout] + 1e-5f);
    float sr = gr[cout] / sqrtf(var_[cout] + 1e-5f);
    float w1 = cl1_w[cout * 128 + cin] * s1;
    float wr = reg1_w[cout * 128 + cin] * sr;
    float w2 = cl2_w[cout * 128 + cin];
    float w3 = cl3_w[cout * 128 + cin];
    ws_f[OFF_W1T + tid] = w1;
    ws_f[OFF_W2T + tid] = w2;
    ws_f[OFF_W3T + tid] = w3;
    int j = cout * 128 + cin;
    unsigned short h;
    h = f2bf(w1); wbf[UW1H + j] = h; wbf[UW1L + j] = f2bf(w1 - bf2f(h));
    h = f2bf(wr); wbf[UWRH + j] = h; wbf[UWRL + j] = f2bf(wr - bf2f(h));
    h = f2bf(w2); wbf[UW2H + j] = h; wbf[UW2L + j] = f2bf(w2 - bf2f(h));
    h = f2bf(w3); wbf[UW3H + j] = h; wbf[UW3L + j] = f2bf(w3 - bf2f(h));
    if (tid < 2048) {               // W3 rows 128..143: mask row then zeros
        int r = tid >> 7, ci = tid & 127;
        float v = (r == 0) ? cl3_w[128 * 128 + ci] : 0.0f;
        int jj = (128 + r) * 128 + ci;
        h = f2bf(v); wbf[UW3H + jj] = h; wbf[UW3L + jj] = f2bf(v - bf2f(h));
    }
    if (tid < 128) {
        float s1b = g1[tid] / sqrtf(va1[tid] + 1e-5f);
        float srb = gr[tid] / sqrtf(var_[tid] + 1e-5f);
        ws_f[OFF_B1F + tid] = cl1_b[tid] * s1b + be1[tid] - mu1[tid] * s1b;
        ws_f[OFF_BRF + tid] = reg1_b[tid] * srb + ber[tid] - mur[tid] * srb;
        ws_f[OFF_B2F + tid] = cl2_b[tid];
        hist[tid * HPAD] = 0;               // padded: one bin per cache line
    }
    if (tid < 129) ws_f[OFF_B3F + tid] = cl3_b[tid];
    if (tid == 0) fixcnt[0] = 0;
}

// ---------------------------------------------------------------------------
// FUSED pipeline on MFMA — R11 structure, unchanged (no hist in epilogue,
// bf16 XRB stores).
// ---------------------------------------------------------------------------
__global__ __launch_bounds__(256, 2)
void k_fused(const float* __restrict__ X, const float* __restrict__ wsf,
             const unsigned short* __restrict__ wbf,
             unsigned short* __restrict__ XRB, float* __restrict__ out_mask,
             int* __restrict__ inds, int* __restrict__ fixcnt,
             int* __restrict__ fixlist)
{
    __shared__ __align__(16) unsigned short XBh[64 * 136];
    __shared__ __align__(16) unsigned short XBl[64 * 136];
    __shared__ float sm1[4 * 64];
    __shared__ float sm2[4 * 64];
    __shared__ int   si1[4 * 64];

    const int t = threadIdx.x;
    const int lane = t & 63;
    const int cl16 = lane & 15;           // col / n within fragment
    const int q8 = (lane >> 4) * 8;       // k-offset within fragment
    const int q4 = (lane >> 4) * 4;       // row-offset within D fragment
    const int wv = __builtin_amdgcn_readfirstlane(t >> 6);
    const unsigned nt64 = blockIdx.x * 64u;
    const unsigned base = nt64 + (nt64 >> 13) * 1040384u;   // b*1048576 + w0

    const unsigned short* W1H = wbf + UW1H; const unsigned short* W1L = wbf + UW1L;
    const unsigned short* WRH = wbf + UWRH; const unsigned short* WRL = wbf + UWRL;
    const unsigned short* W2H = wbf + UW2H; const unsigned short* W2L = wbf + UW2L;
    const unsigned short* W3H = wbf + UW3H; const unsigned short* W3L = wbf + UW3L;
    const float* b1f = wsf + OFF_B1F;
    const float* brf = wsf + OFF_BRF;
    const float* b2f = wsf + OFF_B2F;
    const float* b3f = wsf + OFF_B3F;

    const f32x4 vzero = {0.f, 0.f, 0.f, 0.f};

    // ---- stage x tile -> bf16 hi/lo planes [pos][cin] ----
    {
        const int pos = t & 63, cig = t >> 6;      // cig: 0..3
        #pragma unroll
        for (int l = 0; l < 8; ++l) {
            int ci0 = cig * 32 + l * 4;
            float v0 = X[base + (unsigned)(ci0 + 0) * 8192u + pos];
            float v1 = X[base + (unsigned)(ci0 + 1) * 8192u + pos];
            float v2 = X[base + (unsigned)(ci0 + 2) * 8192u + pos];
            float v3 = X[base + (unsigned)(ci0 + 3) * 8192u + pos];
            unsigned short h0 = f2bf(v0), h1 = f2bf(v1), h2 = f2bf(v2), h3 = f2bf(v3);
            unsigned long long ph = pack4(h0, h1, h2, h3);
            unsigned long long pl = pack4(f2bf(v0 - bf2f(h0)), f2bf(v1 - bf2f(h1)),
                                          f2bf(v2 - bf2f(h2)), f2bf(v3 - bf2f(h3)));
            *(unsigned long long*)&XBh[pos * 136 + ci0] = ph;
            *(unsigned long long*)&XBl[pos * 136 + ci0] = pl;
        }
    }
    __syncthreads();

    // ---- P1: y1 (W1) and xr (WR) in one pass over B frags ----
    f32x4 aY[2][4], aR[2][4];
    #pragma unroll
    for (int m = 0; m < 2; ++m)
        #pragma unroll
        for (int n = 0; n < 4; ++n) { aY[m][n] = vzero; aR[m][n] = vzero; }
    #pragma unroll
    for (int kt = 0; kt < 4; ++kt) {
        bf16x8 Bh[4], Bl[4];
        #pragma unroll
        for (int n = 0; n < 4; ++n) {
            int bo = (n * 16 + cl16) * 136 + kt * 32 + q8;
            Bh[n] = *(const bf16x8*)&XBh[bo];
            Bl[n] = *(const bf16x8*)&XBl[bo];
        }
        #pragma unroll
        for (int m = 0; m < 2; ++m) {
            int ao = (wv * 32 + m * 16 + cl16) * 128 + kt * 32 + q8;
            bf16x8 a1h = *(const bf16x8*)&W1H[ao], a1l = *(const bf16x8*)&W1L[ao];
            bf16x8 arh = *(const bf16x8*)&WRH[ao], arl = *(const bf16x8*)&WRL[ao];
            #pragma unroll
            for (int n = 0; n < 4; ++n) {
                aY[m][n] = MFMA16(a1h, Bl[n], aY[m][n], 0, 0, 0);
                aY[m][n] = MFMA16(a1l, Bh[n], aY[m][n], 0, 0, 0);
                aY[m][n] = MFMA16(a1h, Bh[n], aY[m][n], 0, 0, 0);
                aR[m][n] = MFMA16(arh, Bl[n], aR[m][n], 0, 0, 0);
                aR[m][n] = MFMA16(arl, Bh[n], aR[m][n], 0, 0, 0);
                aR[m][n] = MFMA16(arh, Bh[n], aR[m][n], 0, 0, 0);
            }
        }
    }
    __syncthreads();                       // all P1 reads of XB done

    // xr epilogue -> global XRB[n][c] bf16 (ushort4; 16 rows x 32B contiguous)
    {
        #pragma unroll
        for (int m = 0; m < 2; ++m) {
            int cb = wv * 32 + m * 16 + q4;
            float br0 = brf[cb], br1 = brf[cb + 1], br2 = brf[cb + 2], br3 = brf[cb + 3];
            #pragma unroll
            for (int n = 0; n < 4; ++n) {
                unsigned pb = (nt64 + n * 16 + cl16) * 128u + cb;
                ushort4 xo;
                xo.x = f2bf(lrelu(aR[m][n][0] + br0));
                xo.y = f2bf(lrelu(aR[m][n][1] + br1));
                xo.z = f2bf(lrelu(aR[m][n][2] + br2));
                xo.w = f2bf(lrelu(aR[m][n][3] + br3));
                *(ushort4*)&XRB[pb] = xo;
            }
        }
    }
    // y1 epilogue -> XB planes
    {
        #pragma unroll
        for (int m = 0; m < 2; ++m) {
            int cb = wv * 32 + m * 16 + q4;
            float b0 = b1f[cb], b1 = b1f[cb + 1], b2 = b1f[cb + 2], b3 = b1f[cb + 3];
            #pragma unroll
            for (int n = 0; n < 4; ++n) {
                float v0 = lrelu(aY[m][n][0] + b0), v1 = lrelu(aY[m][n][1] + b1);
                float v2 = lrelu(aY[m][n][2] + b2), v3 = lrelu(aY[m][n][3] + b3);
                unsigned short h0 = f2bf(v0), h1 = f2bf(v1), h2 = f2bf(v2), h3 = f2bf(v3);
                unsigned long long ph = pack4(h0, h1, h2, h3);
                unsigned long long pl = pack4(f2bf(v0 - bf2f(h0)), f2bf(v1 - bf2f(h1)),
                                              f2bf(v2 - bf2f(h2)), f2bf(v3 - bf2f(h3)));
                int idx = (n * 16 + cl16) * 136 + cb;
                *(unsigned long long*)&XBh[idx] = ph;
                *(unsigned long long*)&XBl[idx] = pl;
            }
        }
    }
    __syncthreads();

    // ---- P2: y2 = lrelu(W2 y1 + b2) ----
    f32x4 aZ[2][4];
    #pragma unroll
    for (int m = 0; m < 2; ++m)
        #pragma unroll
        for (int n = 0; n < 4; ++n) aZ[m][n] = vzero;
    #pragma unroll
    for (int kt = 0; kt < 4; ++kt) {
        bf16x8 Bh[4], Bl[4];
        #pragma unroll
        for (int n = 0; n < 4; ++n) {
            int bo = (n * 16 + cl16) * 136 + kt * 32 + q8;
            Bh[n] = *(const bf16x8*)&XBh[bo];
            Bl[n] = *(const bf16x8*)&XBl[bo];
        }
        #pragma unroll
        for (int m = 0; m < 2; ++m) {
            int ao = (wv * 32 + m * 16 + cl16) * 128 + kt * 32 + q8;
            bf16x8 ah = *(const bf16x8*)&W2H[ao], al = *(const bf16x8*)&W2L[ao];
            #pragma unroll
            for (int n = 0; n < 4; ++n) {
                aZ[m][n] = MFMA16(ah, Bl[n], aZ[m][n], 0, 0, 0);
                aZ[m][n] = MFMA16(al, Bh[n], aZ[m][n], 0, 0, 0);
                aZ[m][n] = MFMA16(ah, Bh[n], aZ[m][n], 0, 0, 0);
            }
        }
    }
    __syncthreads();
    {
        #pragma unroll
        for (int m = 0; m < 2; ++m) {
            int cb = wv * 32 + m * 16 + q4;
            float b0 = b2f[cb], b1 = b2f[cb + 1], b2 = b2f[cb + 2], b3 = b2f[cb + 3];
            #pragma unroll
            for (int n = 0; n < 4; ++n) {
                float v0 = lrelu(aZ[m][n][0] + b0), v1 = lrelu(aZ[m][n][1] + b1);
                float v2 = lrelu(aZ[m][n][2] + b2), v3 = lrelu(aZ[m][n][3] + b3);
                unsigned short h0 = f2bf(v0), h1 = f2bf(v1), h2 = f2bf(v2), h3 = f2bf(v3);
                unsigned long long ph = pack4(h0, h1, h2, h3);
                unsigned long long pl = pack4(f2bf(v0 - bf2f(h0)), f2bf(v1 - bf2f(h1)),
                                              f2bf(v2 - bf2f(h2)), f2bf(v3 - bf2f(h3)));
                int idx = (n * 16 + cl16) * 136 + cb;
                *(unsigned long long*)&XBh[idx] = ph;
                *(unsigned long long*)&XBl[idx] = pl;
            }
        }
    }
    __syncthreads();

    // ---- P3: logits (+ mask row on wave 3) ----
    f32x4 aL[2][4], aM[4];
    #pragma unroll
    for (int m = 0; m < 2; ++m)
        #pragma unroll
        for (int n = 0; n < 4; ++n) aL[m][n] = vzero;
    #pragma unroll
    for (int n = 0; n < 4; ++n) aM[n] = vzero;
    #pragma unroll
    for (int kt = 0; kt < 4; ++kt) {
        bf16x8 Bh[4], Bl[4];
        #pragma unroll
        for (int n = 0; n < 4; ++n) {
            int bo = (n * 16 + cl16) * 136 + kt * 32 + q8;
            Bh[n] = *(const bf16x8*)&XBh[bo];
            Bl[n] = *(const bf16x8*)&XBl[bo];
        }
        #pragma unroll
        for (int m = 0; m < 2; ++m) {
            int ao = (wv * 32 + m * 16 + cl16) * 128 + kt * 32 + q8;
            bf16x8 ah = *(const bf16x8*)&W3H[ao], al = *(const bf16x8*)&W3L[ao];
            #pragma unroll
            for (int n = 0; n < 4; ++n) {
                aL[m][n] = MFMA16(ah, Bl[n], aL[m][n], 0, 0, 0);
                aL[m][n] = MFMA16(al, Bh[n], aL[m][n], 0, 0, 0);
                aL[m][n] = MFMA16(ah, Bh[n], aL[m][n], 0, 0, 0);
            }
        }
        if (wv == 3) {   // mask row block (rows 128..143, only row 128 used)
            int ao = (128 + cl16) * 128 + kt * 32 + q8;
            bf16x8 ah = *(const bf16x8*)&W3H[ao], al = *(const bf16x8*)&W3L[ao];
            #pragma unroll
            for (int n = 0; n < 4; ++n) {
                aM[n] = MFMA16(ah, Bl[n], aM[n], 0, 0, 0);
                aM[n] = MFMA16(al, Bh[n], aM[n], 0, 0, 0);
                aM[n] = MFMA16(ah, Bh[n], aM[n], 0, 0, 0);
            }
        }
    }

    // per-lane top-2 over its 8 couts (ascending cout = numpy first-tie rule)
    {
        float bb[2][4];
        #pragma unroll
        for (int m = 0; m < 2; ++m) {
            int cb = wv * 32 + m * 16 + q4;
            bb[m][0] = b3f[cb]; bb[m][1] = b3f[cb + 1];
            bb[m][2] = b3f[cb + 2]; bb[m][3] = b3f[cb + 3];
        }
        float m1[4], m2[4]; int i1[4];
        #pragma unroll
        for (int n = 0; n < 4; ++n) {
            m1[n] = -1e30f; m2[n] = -1e30f; i1[n] = 0;
            #pragma unroll
            for (int m = 0; m < 2; ++m) {
                int cb = wv * 32 + m * 16 + q4;
                #pragma unroll
                for (int r = 0; r < 4; ++r) {
                    float v = aL[m][n][r] + bb[m][r];
                    if (v > m1[n]) { m2[n] = m1[n]; m1[n] = v; i1[n] = cb + r; }
                    else if (v > m2[n]) m2[n] = v;
                }
            }
        }
        #pragma unroll
        for (int off = 16; off <= 32; off <<= 1) {
            #pragma unroll
            for (int n = 0; n < 4; ++n) {
                float om1 = __shfl_xor(m1[n], off);
                float om2 = __shfl_xor(m2[n], off);
                int   oi1 = __shfl_xor(i1[n], off);
                if (om1 > m1[n] || (om1 == m1[n] && oi1 < i1[n])) {
                    m2[n] = fmaxf(m1[n], om2); m1[n] = om1; i1[n] = oi1;
                } else {
                    m2[n] = fmaxf(m2[n], om1);
                }
            }
        }
        if ((lane >> 4) == 0) {
            #pragma unroll
            for (int n = 0; n < 4; ++n) {
                sm1[wv * 64 + n * 16 + cl16] = m1[n];
                sm2[wv * 64 + n * 16 + cl16] = m2[n];
                si1[wv * 64 + n * 16 + cl16] = i1[n];
            }
        }
    }
    if (wv == 3 && (lane >> 4) == 0) {
        float mb = b3f[128];
        #pragma unroll
        for (int n = 0; n < 4; ++n)
            out_mask[nt64 + n * 16 + cl16] = lrelu(aM[n][0] + mb);
    }
    __syncthreads();
    if (t < 64) {
        float m1 = sm1[t], m2 = sm2[t];
        int i1 = si1[t];
        #pragma unroll
        for (int w = 1; w < 4; ++w) {     // ascending wv = ascending cout
            float v1 = sm1[w * 64 + t];
            float v2 = sm2[w * 64 + t];
            int   vi = si1[w * 64 + t];
            if (v1 > m1) { m2 = fmaxf(m1, v2); m1 = v1; i1 = vi; }
            else         { m2 = fmaxf(m2, v1); }
        }
        int n = nt64 + t;
        inds[n] = i1;
        if (m1 - m2 < DELTA) {
            int slot = atomicAdd(fixcnt, 1);
            fixlist[slot] = n;
        }
    }
}

// ---------------------------------------------------------------------------
// fixup: ONE WAVE per flagged position, exact fp32, lane-coalesced weights.
// Updates inds only (hist built afterwards by k_hist).
// ---------------------------------------------------------------------------
__global__ __launch_bounds__(256, 4)
void k_fix(const float* __restrict__ X, const float* __restrict__ wsf,
           const int* __restrict__ fixcnt, const int* __restrict__ fixlist,
           int* __restrict__ inds)
{
    const int cnt = fixcnt[0];
    const int t = threadIdx.x;
    const int lane = t & 63;
    const int wv = t >> 6;
    const float* W1T = wsf + OFF_W1T;
    const float* W2T = wsf + OFF_W2T;
    const float* W3T = wsf + OFF_W3T;
    const float* b1f = wsf + OFF_B1F;
    const float* b2f = wsf + OFF_B2F;
    const float* b3f = wsf + OFF_B3F;

    for (int idx = blockIdx.x * 4 + wv; idx < cnt; idx += 1024) {
        int n = fixlist[idx];
        const float* xb = X + (unsigned)(n >> 13) * 1048576u + (unsigned)(n & 8191);
        float x0 = xb[(unsigned)lane * 8192u];
        float x1 = xb[(unsigned)(64 + lane) * 8192u];
        float a0, a1;
        a0 = 0.f; a1 = 0.f;
        for (int ci = 0; ci < 64; ++ci) {
            float xv = __shfl(x0, ci);
            const float* wr = W1T + ci * 128;
            a0 = fmaf(wr[lane], xv, a0);
            a1 = fmaf(wr[64 + lane], xv, a1);
        }
        for (int ci = 0; ci < 64; ++ci) {
            float xv = __shfl(x1, ci);
            const float* wr = W1T + (64 + ci) * 128;
            a0 = fmaf(wr[lane], xv, a0);
            a1 = fmaf(wr[64 + lane], xv, a1);
        }
        x0 = lrelu(a0 + b1f[lane]); x1 = lrelu(a1 + b1f[64 + lane]);
        a0 = 0.f; a1 = 0.f;
        for (int ci = 0; ci < 64; ++ci) {
            float xv = __shfl(x0, ci);
            const float* wr = W2T + ci * 128;
            a0 = fmaf(wr[lane], xv, a0);
            a1 = fmaf(wr[64 + lane], xv, a1);
        }
        for (int ci = 0; ci < 64; ++ci) {
            float xv = __shfl(x1, ci);
            const float* wr = W2T + (64 + ci) * 128;
            a0 = fmaf(wr[lane], xv, a0);
            a1 = fmaf(wr[64 + lane], xv, a1);
        }
        x0 = lrelu(a0 + b2f[lane]); x1 = lrelu(a1 + b2f[64 + lane]);
        a0 = 0.f; a1 = 0.f;
        for (int ci = 0; ci < 64; ++ci) {
            float xv = __shfl(x0, ci);
            const float* wr = W3T + ci * 128;
            a0 = fmaf(wr[lane], xv, a0);
            a1 = fmaf(wr[64 + lane], xv, a1);
        }
        for (int ci = 0; ci < 64; ++ci) {
            float xv = __shfl(x1, ci);
            const float* wr = W3T + (64 + ci) * 128;
            a0 = fmaf(wr[lane], xv, a0);
            a1 = fmaf(wr[64 + lane], xv, a1);
        }
        float L0 = a0 + b3f[lane], L1 = a1 + b3f[64 + lane];
        float v; int id;
        if (L0 >= L1) { v = L0; id = lane; } else { v = L1; id = 64 + lane; }
        #pragma unroll
        for (int off = 1; off < 64; off <<= 1) {
            float ov = __shfl_xor(v, off);
            int   oi = __shfl_xor(id, off);
            if (ov > v || (ov == v && oi < id)) { v = ov; id = oi; }
        }
        if (lane == 0) inds[n] = id;
    }
}

// histogram from final inds — block-aggregated; PADDED bins (1 line/bin)
__global__ void k_hist(const int* __restrict__ inds, int* __restrict__ hist)
{
    __shared__ int lh[128];
    int t = threadIdx.x;
    if (t < 128) lh[t] = 0;
    __syncthreads();
    atomicAdd(&lh[inds[blockIdx.x * 256 + t]], 1);
    __syncthreads();
    if (t < 128 && lh[t] > 0) atomicAdd(&hist[t * HPAD], lh[t]);
}

// exclusive scan of histogram + build tile work-queue (64 positions per tile)
__global__ void k_scan(const int* __restrict__ hist, int* __restrict__ off,
                       int* __restrict__ cur, int* __restrict__ tiles,
                       int* __restrict__ ntt)
{
    __shared__ int s[128];
    __shared__ int s2[128];
    int t = threadIdx.x;
    int v = hist[t * HPAD];
    int ntk = (v + 63) >> 6;
    s[t] = v;
    s2[t] = ntk;
    __syncthreads();
    for (int d = 1; d < 128; d <<= 1) {
        int a  = (t >= d) ? s[t - d]  : 0;
        int a2 = (t >= d) ? s2[t - d] : 0;
        __syncthreads();
        s[t] += a;
        s2[t] += a2;
        __syncthreads();
    }
    off[t] = s[t] - v;
    cur[t * HPAD] = s[t] - v;
    int tb = s2[t] - ntk;
    for (int j = 0; j < ntk; ++j)
        tiles[tb + j] = (t << 16) | j;
    if (t == 127) ntt[0] = s2[127];
}

// scatter positions into buckets, block-aggregated; PADDED cur bins
__global__ void k_scatter(const int* __restrict__ inds, int* __restrict__ cur,
                          int* __restrict__ bucket)
{
    __shared__ int lh[128];
    __shared__ int gb[128];
    int t = threadIdx.x;
    if (t < 128) lh[t] = 0;
    __syncthreads();
    int n = blockIdx.x * 256 + t;
    int id = inds[n];
    int r = atomicAdd(&lh[id], 1);
    __syncthreads();
    if (t < 128 && lh[t] > 0) gb[t] = atomicAdd(&cur[t * HPAD], lh[t]);
    __syncthreads();
    bucket[gb[id] + r] = n;
}

// bucketed per-position MLP on MFMA bf16, tile = 64 positions, bf16 gather.
__global__ __launch_bounds__(256, 4)
void k_reg(const unsigned short* __restrict__ XRB, const unsigned short* __restrict__ wbf,
           const float* __restrict__ cm2b, const float* __restrict__ cm3w,
           const float* __restrict__ cm3b, const int* __restrict__ hist,
           const int* __restrict__ off, const int* __restrict__ bucket,
           const int* __restrict__ tiles, const int* __restrict__ ntt,
           float* __restrict__ out)
{
    __shared__ __align__(16) unsigned short XP[4 * NST];
    __shared__ float red[64];
    int bid = blockIdx.x;
    if (bid >= ntt[0]) return;
    int desc = tiles[bid];
    int k = desc >> 16;
    int start = (desc & 0xffff) << 6;
    int cnt = hist[k * HPAD];
    int base = off[k];
    int t = threadIdx.x;
    int lane = t & 63;
    int wv = __builtin_amdgcn_readfirstlane(t >> 6);
    const int n16 = lane & 15;
    const int quad = lane >> 4;

    // gather 64 xr rows (256 B bf16 each) -> frag-major LDS; 4 threads/row
    {
        int rs = t >> 2;                         // 0..63
        int q = t & 3;                           // = kt
        int sidx = start + rs;
        if (sidx >= cnt) sidx = cnt - 1;
        int n = bucket[base + sidx];
        const uint4* src = (const uint4*)(XRB + (unsigned)n * 128u + q * 32);
        uint4 a0 = src[0], a1 = src[1], a2 = src[2], a3 = src[3];
        unsigned db = (rs >> 4) * NST + q * 512 + (rs & 15) * 8;
        *(uint4*)&XP[db]       = a0;             // quad 0
        *(uint4*)&XP[db + 128] = a1;             // quad 1
        *(uint4*)&XP[db + 256] = a2;             // quad 2
        *(uint4*)&XP[db + 384] = a3;             // quad 3
    }
    __syncthreads();

    // B-frags: W2k^T [out][ci]
    const unsigned short* wb = wbf + UW2K + (unsigned)k * 4096u;
    bf16x8 Bf[2][4];
    #pragma unroll
    for (int nf = 0; nf < 2; ++nf)
        #pragma unroll
        for (int kt = 0; kt < 4; ++kt)
            Bf[nf][kt] = *(const bf16x8*)&wb[(nf * 16 + n16) * 128 + kt * 32 + quad * 8];

    const f32x4 vzero = {0.f, 0.f, 0.f, 0.f};
    f32x4 acc[2];
    acc[0] = vzero; acc[1] = vzero;
    #pragma unroll
    for (int kt = 0; kt < 4; ++kt) {
        bf16x8 Af = *(const bf16x8*)&XP[wv * NST + kt * 512 + lane * 8];
        #pragma unroll
        for (int nf = 0; nf < 2; ++nf)
            acc[nf] = MFMA16(Af, Bf[nf][kt], acc[nf], 0, 0, 0);
    }

    // epilogue: lane's 2 outs -> partial; shfl-reduce over 16-lane out dim
    float b2a = cm2b[k * 32 + n16], b2b = cm2b[k * 32 + 16 + n16];
    float w3a = cm3w[k * 32 + n16], w3b = cm3w[k * 32 + 16 + n16];
    #pragma unroll
    for (int r = 0; r < 4; ++r) {
        float p = lrelu(acc[0][r] + b2a) * w3a
                + lrelu(acc[1][r] + b2b) * w3b;
        p += __shfl_xor(p, 1);
        p += __shfl_xor(p, 2);
        p += __shfl_xor(p, 4);
        p += __shfl_xor(p, 8);
        if (n16 == 0)
            red[wv * 16 + quad * 4 + r] = p;
    }
    __syncthreads();
    if (t < 64 && start + t < cnt) {
        int n2 = bucket[base + start + t];
        out[n2] = ((float)k + red[t] + cm3b[k]) * (1.0f / 128.0f);
    }
}

extern "C" void kernel_launch(void* const* d_in, const int* in_sizes, int n_in,
                              void* d_out, int out_size, void* d_ws, size_t ws_size,
                              hipStream_t stream)
{
    (void)in_sizes; (void)n_in; (void)out_size; (void)ws_size;
    const float* x_in   = (const float*)d_in[0];
    const float* cl1_w  = (const float*)d_in[1];
    const float* cl1_b  = (const float*)d_in[2];
    const float* g1     = (const float*)d_in[3];
    const float* be1    = (const float*)d_in[4];
    const float* mu1    = (const float*)d_in[5];
    const float* va1    = (const float*)d_in[6];
    const float* cl2_w  = (const float*)d_in[7];
    const float* cl2_b  = (const float*)d_in[8];
    const float* cl3_w  = (const float*)d_in[9];
    const float* cl3_b  = (const float*)d_in[10];
    const float* reg1_w = (const float*)d_in[11];
    const float* reg1_b = (const float*)d_in[12];
    const float* gr     = (const float*)d_in[13];
    const float* ber    = (const float*)d_in[14];
    const float* mur    = (const float*)d_in[15];
    const float* var_   = (const float*)d_in[16];
    const float* cm2w   = (const float*)d_in[17];
    const float* cm2b   = (const float*)d_in[18];
    const float* cm3w   = (const float*)d_in[19];
    const float* cm3b   = (const float*)d_in[20];

    float* ws_f = (float*)d_ws;
    unsigned short* XRB = (unsigned short*)(ws_f + OFF_XR);
    unsigned short* wbf = (unsigned short*)(ws_f + OFF_BF16);
    int*   wsi    = (int*)(ws_f + OFF_INT);
    int*   inds   = wsi;
    int*   hist   = inds + 65536;          // 128*HPAD = 2048 ints (padded)
    int*   offb   = hist + 2048;
    int*   cur    = offb + 128;            // 128*HPAD = 2048 ints (padded)
    int*   ntt    = cur + 2048;
    int*   fixcnt = ntt + 4;
    int*   tiles  = fixcnt + 4;
    int*   fixlist= tiles + 1536;
    int*   bucket = fixlist + 65536;
    float* out = (float*)d_out;

    hipLaunchKernelGGL(k_prep, dim3(256), dim3(128), 0, stream,
                       cl1_w, cl1_b, g1, be1, mu1, va1, cl2_w, cl2_b, cl3_w, cl3_b,
                       reg1_w, reg1_b, gr, ber, mur, var_, cm2w, ws_f, wbf, hist, fixcnt);
    hipLaunchKernelGGL(k_fused, dim3(1024), dim3(256), 0, stream,
                       x_in, ws_f, wbf, XRB, out + 65536, inds, fixcnt, fixlist);
    hipLaunchKernelGGL(k_fix, dim3(256), dim3(256), 0, stream,
                       x_in, ws_f, fixcnt, fixlist, inds);
    hipLaunchKernelGGL(k_hist, dim3(256), dim3(256), 0, stream, inds, hist);
    hipLaunchKernelGGL(k_scan, dim3(1), dim3(128), 0, stream,
                       hist, offb, cur, tiles, ntt);
    hipLaunchKernelGGL(k_scatter, dim3(256), dim3(256), 0, stream, inds, cur, bucket);
    hipLaunchKernelGGL(k_reg, dim3(1536), dim3(256), 0, stream,
                       XRB, wbf, cm2b, cm3w, cm3b, hist, offb, bucket, tiles, ntt, out);
}